// Round 5
// baseline (230.125 us; speedup 1.0000x reference)
//
#include <hip/hip_runtime.h>
#include <stdint.h>

// ---- problem dims ----
#define NB   32
#define CIN  128
#define COUT 256
#define HH   56
#define WW   56
#define S1   (HH*WW)      // 3136
#define HO   28
#define WO   28
#define S2   (HO*WO)      // 784
#define NS1  (NB*S1)      // 100352
#define NS2  (NB*S2)      // 25088
#define TOT2 (NS2*COUT)   // 6422528
#define EPSV 1e-5f

// ---- workspace layout (bytes) ----
constexpr size_t OFF_XBITS = 0;                                 // NS1*8*4 = 3,211,264
constexpr size_t OFF_WB1   = OFF_XBITS + (size_t)NS1*8*4;       // 8 KB
constexpr size_t OFF_WB3   = OFF_WB1 + 256*8*4;                 // 16 KB
constexpr size_t OFF_WDW   = OFF_WB3 + 256*16*4;                // 4 KB
constexpr size_t OFF_ACC   = OFF_WDW + 4096;                    // 3*256*4 int = 12 KB
constexpr size_t OFF_THR   = OFF_ACC + 3*256*4*sizeof(int);     // 4*256 int = 4 KB
constexpr size_t OFF_WADJT = OFF_THR + 4*256*sizeof(int);       // 128*256*4 = 131,072
constexpr size_t OFF_OUT1  = OFF_WADJT + (size_t)CIN*COUT*4;    // NS1*COUT i8 = 25,690,112
constexpr size_t OFF_OUT2  = OFF_OUT1 + (size_t)NS1*COUT;       // i8 6,422,528
constexpr size_t OFF_XB2   = OFF_OUT2 + (size_t)TOT2;           // NS2*16*4 = 1,605,632
constexpr size_t OFF_OUT3  = OFF_XB2 + (size_t)NS2*16*4;        // i16 12,845,056
// total ~50 MB

// finalize BN scale/shift from exact integer sums of prelu output
__device__ __forceinline__ void bn_finalize(const int* __restrict__ acc4,
                                            float a, float g, float b, float inv_ns,
                                            float& sc, float& sh) {
  float ps = (float)acc4[0];   // sum of v where v>0
  float ng = (float)acc4[1];   // sum of v where v<0
  float pq = (float)acc4[2];   // sum of v^2 where v>0
  float nq = (float)acc4[3];   // sum of v^2 where v<0
  float mean = (ps + a*ng) * inv_ns;
  float ex2  = (pq + a*a*nq) * inv_ns;
  float var  = ex2 - mean*mean;
  float rs   = rsqrtf(var + EPSV);
  sc = rs * g;
  sh = b - mean * sc;
}

// ---------------- pack weights: bitplanes + dw signs + wadj transpose ----------------
__global__ __launch_bounds__(64) void packw_kernel(
    const float* __restrict__ w1, const float* __restrict__ w3,
    const float* __restrict__ wdw, const float* __restrict__ wadj,
    uint32_t* __restrict__ wb1, uint32_t* __restrict__ wb3,
    int8_t* __restrict__ wdws, float* __restrict__ wadjT) {
  int co = blockIdx.x;
  int l  = threadIdx.x;
  for (int h = 0; h < 2; ++h) {
    float v = w1[(size_t)co*CIN + h*64 + l];
    unsigned long long bp = __ballot(v > 0.f);
    unsigned long long bn = __ballot(v < 0.f);
    if (l == 0) {
      wb1[co*8 + 2*h    ] = (uint32_t)bp;
      wb1[co*8 + 2*h + 1] = (uint32_t)(bp >> 32);
      wb1[co*8 + 4 + 2*h    ] = (uint32_t)bn;
      wb1[co*8 + 4 + 2*h + 1] = (uint32_t)(bn >> 32);
    }
  }
  for (int h = 0; h < 4; ++h) {
    float v = w3[(size_t)co*COUT + h*64 + l];
    unsigned long long bp = __ballot(v > 0.f);
    unsigned long long bn = __ballot(v < 0.f);
    if (l == 0) {
      wb3[co*16 + 2*h    ] = (uint32_t)bp;
      wb3[co*16 + 2*h + 1] = (uint32_t)(bp >> 32);
      wb3[co*16 + 8 + 2*h    ] = (uint32_t)bn;
      wb3[co*16 + 8 + 2*h + 1] = (uint32_t)(bn >> 32);
    }
  }
  if (l < 9) {
    float v = wdw[co*9 + l];
    wdws[co*9 + l] = (int8_t)((v > 0.f) - (v < 0.f));
  }
  // transpose w_adj: wadjT[c][co] = wadj[co][c]
  #pragma unroll
  for (int k = 0; k < 2; ++k) {
    int c = 2*l + k;
    wadjT[(size_t)c*COUT + co] = wadj[(size_t)co*CIN + c];
  }
}

// ---------------- pack x into bitplanes over C (split over wdx) ----------------
__global__ __launch_bounds__(256) void packx_kernel(
    const float* __restrict__ x, uint32_t* __restrict__ xbits) {
  int m = blockIdx.x*256 + threadIdx.x;     // m = n*S1 + hw
  int wdx = blockIdx.y;                     // 0..3
  int n = m / S1, hw = m % S1;
  size_t base = ((size_t)n*CIN + wdx*32)*S1 + hw;
  uint32_t p = 0, q = 0;
  #pragma unroll
  for (int j = 0; j < 32; ++j) {
    float v = x[base + (size_t)j*S1];
    p |= (uint32_t)(v > 0.f) << j;
    q |= (uint32_t)(v < 0.f) << j;
  }
  xbits[(size_t)m*8 + wdx    ] = p;
  xbits[(size_t)m*8 + 4 + wdx] = q;
}

// ---------------- conv1: binary 1x1 via bitplane popcount ----------------
__global__ __launch_bounds__(256) void conv1_kernel(
    const uint32_t* __restrict__ xb, const uint32_t* __restrict__ wb,
    int8_t* __restrict__ out1) {
  int m = blockIdx.x*256 + threadIdx.x;
  int n = m / S1, hw = m % S1;
  const uint32_t* xw = xb + (size_t)m*8;
  uint32_t p0 = xw[0], p1 = xw[1], p2 = xw[2], p3 = xw[3];
  uint32_t q0 = xw[4], q1 = xw[5], q2 = xw[6], q3 = xw[7];
  int co0 = blockIdx.y * 32;
  size_t obase = ((size_t)n*COUT)*S1 + hw;
  #pragma unroll 4
  for (int co = co0; co < co0 + 32; ++co) {
    const uint32_t* w8 = wb + (size_t)co*8;
    uint32_t a0 = w8[0], a1 = w8[1], a2 = w8[2], a3 = w8[3];
    uint32_t b0 = w8[4], b1 = w8[5], b2 = w8[6], b3 = w8[7];
    int acc = __popc(p0&a0) + __popc(p1&a1) + __popc(p2&a2) + __popc(p3&a3)
            + __popc(q0&b0) + __popc(q1&b1) + __popc(q2&b2) + __popc(q3&b3)
            - __popc(p0&b0) - __popc(p1&b1) - __popc(p2&b2) - __popc(p3&b3)
            - __popc(q0&a0) - __popc(q1&a1) - __popc(q2&a2) - __popc(q3&a3);
    if (acc > 127) acc = 127;   // +128 would wrap int8; prob ~2^-128
    out1[obase + (size_t)co*S1] = (int8_t)acc;
  }
}

// ---------------- per-channel integer stats (int8 buffer) ----------------
__global__ __launch_bounds__(256) void stats_i8_kernel(
    const int8_t* __restrict__ buf, int* __restrict__ accum,
    int s_sp, int quads_per_block) {
  int co = blockIdx.x, slice = blockIdx.y;
  int q0 = slice * quads_per_block;
  int psum = 0, nsum = 0, psq = 0, nsq = 0;
  for (int i = threadIdx.x; i < quads_per_block; i += 256) {
    int flat = (q0 + i) * 4;
    int n = flat / s_sp, hw = flat % s_sp;
    char4 v = *reinterpret_cast<const char4*>(buf + (size_t)(n*COUT + co)*s_sp + hw);
    int vs[4] = {v.x, v.y, v.z, v.w};
    #pragma unroll
    for (int k = 0; k < 4; ++k) {
      int f = vs[k];
      if (f > 0) { psum += f; psq += f*f; } else { nsum += f; nsq += f*f; }
    }
  }
  __shared__ int r0[256], r1[256], r2[256], r3[256];
  int t = threadIdx.x;
  r0[t] = psum; r1[t] = nsum; r2[t] = psq; r3[t] = nsq;
  __syncthreads();
  for (int s = 128; s > 0; s >>= 1) {
    if (t < s) { r0[t]+=r0[t+s]; r1[t]+=r1[t+s]; r2[t]+=r2[t+s]; r3[t]+=r3[t+s]; }
    __syncthreads();
  }
  if (t == 0) {
    atomicAdd(&accum[co*4+0], r0[0]);
    atomicAdd(&accum[co*4+1], r1[0]);
    atomicAdd(&accum[co*4+2], r2[0]);
    atomicAdd(&accum[co*4+3], r3[0]);
  }
}

__global__ __launch_bounds__(256) void stats_i16_kernel(
    const int16_t* __restrict__ buf, int* __restrict__ accum,
    int s_sp, int pairs_per_block) {
  int co = blockIdx.x, slice = blockIdx.y;
  int p0i = slice * pairs_per_block;
  int psum = 0, nsum = 0, psq = 0, nsq = 0;
  for (int i = threadIdx.x; i < pairs_per_block; i += 256) {
    int flat = (p0i + i) * 2;
    int n = flat / s_sp, hw = flat % s_sp;
    short2 v = *reinterpret_cast<const short2*>(buf + (size_t)(n*COUT + co)*s_sp + hw);
    int vs[2] = {v.x, v.y};
    #pragma unroll
    for (int k = 0; k < 2; ++k) {
      int f = vs[k];
      if (f > 0) { psum += f; psq += f*f; } else { nsum += f; nsq += f*f; }
    }
  }
  __shared__ int r0[256], r1[256], r2[256], r3[256];
  int t = threadIdx.x;
  r0[t] = psum; r1[t] = nsum; r2[t] = psq; r3[t] = nsq;
  __syncthreads();
  for (int s = 128; s > 0; s >>= 1) {
    if (t < s) { r0[t]+=r0[t+s]; r1[t]+=r1[t+s]; r2[t]+=r2[t+s]; r3[t]+=r3[t+s]; }
    __syncthreads();
  }
  if (t == 0) {
    atomicAdd(&accum[co*4+0], r0[0]);
    atomicAdd(&accum[co*4+1], r1[0]);
    atomicAdd(&accum[co*4+2], r2[0]);
    atomicAdd(&accum[co*4+3], r3[0]);
  }
}

// ---------------- thresholds: sign(BN(prelu(v))) == (v>=Tpos) - (v<=Tneg) ----------------
// exact: evaluates the identical float expression at every integer v in range.
// valid because tv is monotone nondecreasing in v (a>0, sc>0 for this problem).
__global__ __launch_bounds__(256) void thr_kernel(
    const int* __restrict__ accum, const float* __restrict__ a,
    const float* __restrict__ g, const float* __restrict__ b,
    float inv_ns, int vlo, int vhi,
    int* __restrict__ Tpos, int* __restrict__ Tneg) {
  int co = threadIdx.x;
  float av = a[co], sc, sh;
  bn_finalize(accum + co*4, av, g[co], b[co], inv_ns, sc, sh);
  int tp = vhi + 1, tn = vlo - 1;
  for (int v = vlo; v <= vhi; ++v) {
    float f = (float)v;
    float p = f > 0.f ? f : av*f;
    float tv = p*sc + sh;
    if (tv > 0.f && v < tp) tp = v;    // min v with tv>0
    if (tv < 0.f && v > tn) tn = v;    // max v with tv<0
  }
  Tpos[co] = tp;
  Tneg[co] = tn;
}

// ---------------- depthwise 3x3 s2 p1 on thresholded signs + fused stats2 ----------------
// one block per (n,co) slab; LDS-staged padded sign tile; 9 int-mad taps per output.
#define DWH 58
#define DWW 60
__global__ __launch_bounds__(256) void dw_kernel(
    const int8_t* __restrict__ out1, const int8_t* __restrict__ wdws,
    const int* __restrict__ Tp1, const int* __restrict__ Tn1,
    int8_t* __restrict__ out2, int* __restrict__ accum2) {
  int nc = blockIdx.x;          // n*COUT + co
  int co = nc & (COUT-1);
  int tid = threadIdx.x;
  __shared__ int8_t sl[DWH][DWW];   // padded sign tile (zeros = conv zero-pad)
  // zero the tile
  int* slw = (int*)&sl[0][0];
  for (int i = tid; i < DWH*DWW/4; i += 256) slw[i] = 0;
  __syncthreads();

  int Tp = Tp1[co], Tn = Tn1[co];
  const char4* src4 = (const char4*)(out1 + (size_t)nc * S1);
  // stage: thresholded signs into padded tile
  for (int q = tid; q < S1/4; q += 256) {
    char4 v4 = src4[q];
    int ih = (4*q) / WW;
    int iw = (4*q) % WW;
    int8_t* dst = &sl[ih+1][iw+1];
    int vs[4] = {v4.x, v4.y, v4.z, v4.w};
    #pragma unroll
    for (int k = 0; k < 4; ++k)
      dst[k] = (int8_t)((vs[k] >= Tp) - (vs[k] <= Tn));
  }
  __syncthreads();

  int w[9];
  #pragma unroll
  for (int k = 0; k < 9; ++k) w[k] = wdws[co*9 + k];

  int psum = 0, nsum = 0, psq = 0, nsq = 0;
  size_t obase = (size_t)nc * S2;
  for (int hw2 = tid; hw2 < S2; hw2 += 256) {
    int ho = hw2 / WO, wo = hw2 % WO;
    int r = 2*ho, c = 2*wo;
    int acc = 0;
    #pragma unroll
    for (int kh = 0; kh < 3; ++kh)
      #pragma unroll
      for (int kw = 0; kw < 3; ++kw)
        acc += (int)sl[r+kh][c+kw] * w[kh*3+kw];
    out2[obase + hw2] = (int8_t)acc;
    if (acc > 0) { psum += acc; psq += acc*acc; } else { nsum += acc; nsq += acc*acc; }
  }

  // fused stats2 block-reduce
  __shared__ int r0[256], r1[256], r2[256], r3[256];
  r0[tid] = psum; r1[tid] = nsum; r2[tid] = psq; r3[tid] = nsq;
  __syncthreads();
  for (int s = 128; s > 0; s >>= 1) {
    if (tid < s) { r0[tid]+=r0[tid+s]; r1[tid]+=r1[tid+s]; r2[tid]+=r2[tid+s]; r3[tid]+=r3[tid+s]; }
    __syncthreads();
  }
  if (tid == 0) {
    atomicAdd(&accum2[co*4+0], r0[0]);
    atomicAdd(&accum2[co*4+1], r1[0]);
    atomicAdd(&accum2[co*4+2], r2[0]);
    atomicAdd(&accum2[co*4+3], r3[0]);
  }
}

// ---------------- pack sign(BN2(prelu(out2))) via thresholds, split over wdx ----------------
__global__ __launch_bounds__(256) void pack2_kernel(
    const int8_t* __restrict__ out2,
    const int* __restrict__ Tp2, const int* __restrict__ Tn2,
    uint32_t* __restrict__ xb2) {
  int m = blockIdx.x*256 + threadIdx.x;   // n*S2 + hw
  int wdx = blockIdx.y;                   // 0..7
  int n = m / S2, hw = m % S2;
  uint32_t p = 0, q = 0;
  #pragma unroll
  for (int j = 0; j < 32; ++j) {
    int c = wdx*32 + j;
    int v = out2[(size_t)(n*COUT + c)*S2 + hw];
    p |= (uint32_t)(v >= Tp2[c]) << j;
    q |= (uint32_t)(v <= Tn2[c]) << j;
  }
  xb2[(size_t)m*16 + wdx    ] = p;
  xb2[(size_t)m*16 + 8 + wdx] = q;
}

// ---------------- conv3: binary 1x1 256->256 ----------------
__global__ __launch_bounds__(256) void conv3_kernel(
    const uint32_t* __restrict__ xb2, const uint32_t* __restrict__ wb3,
    int16_t* __restrict__ out3) {
  int m = blockIdx.x*256 + threadIdx.x;   // NS2
  int n = m / S2, hw = m % S2;
  const uint32_t* xw = xb2 + (size_t)m*16;
  uint32_t P[8], Q[8];
  #pragma unroll
  for (int i = 0; i < 8; ++i) { P[i] = xw[i]; Q[i] = xw[8+i]; }
  int co0 = blockIdx.y * 32;
  size_t obase = ((size_t)n*COUT)*S2 + hw;
  #pragma unroll 2
  for (int co = co0; co < co0 + 32; ++co) {
    const uint32_t* w = wb3 + (size_t)co*16;
    int acc = 0;
    #pragma unroll
    for (int i = 0; i < 8; ++i) {
      uint32_t wp = w[i], wn = w[8+i];
      acc += __popc(P[i]&wp) + __popc(Q[i]&wn) - __popc(P[i]&wn) - __popc(Q[i]&wp);
    }
    out3[obase + (size_t)co*S2] = (int16_t)acc;
  }
}

// ---------------- fused residual (fp32 1x1 s2) + BN3(prelu(out3)) + add ----------------
#define TILE_M 64
__global__ __launch_bounds__(512, 2) void resfinal_kernel(
    const float* __restrict__ x, const float* __restrict__ wadjT,
    const int16_t* __restrict__ out3,
    const float* __restrict__ a3, const float* __restrict__ g3,
    const float* __restrict__ b3, const int* __restrict__ acc3,
    float* __restrict__ out) {
  __shared__ float xt[CIN][TILE_M];                 // 32 KB
  __shared__ float scs[128], shs[128], avs[128];    // 1.5 KB
  int tid = threadIdx.x;
  int m0 = blockIdx.x * TILE_M;
  int coh = blockIdx.y * 128;

  if (tid < 128) {
    int co = coh + tid;
    float sc, sh;
    bn_finalize(acc3 + co*4, a3[co], g3[co], b3[co], 1.f/NS2, sc, sh);
    scs[tid] = sc; shs[tid] = sh; avs[tid] = a3[co];
  }
  #pragma unroll
  for (int k = 0; k < 16; ++k) {
    int idx = k*512 + tid;
    int c  = idx >> 6;
    int ml = idx & 63;
    int m = m0 + ml;
    int n = m / S2, hw = m % S2;
    int ho = hw / WO, wo = hw % WO;
    xt[c][ml] = x[((size_t)n*CIN + c)*S1 + (size_t)(2*ho)*WW + 2*wo];
  }
  __syncthreads();

  int ml  = tid & 63;
  int cg  = __builtin_amdgcn_readfirstlane(tid >> 6);  // wave-uniform 0..7
  int col = cg * 16;
  const float* wT = wadjT + coh + col;

  float acc[16];
  #pragma unroll
  for (int j = 0; j < 16; ++j) acc[j] = 0.f;

  #pragma unroll 2
  for (int c = 0; c < CIN; ++c) {
    float xv = xt[c][ml];
    #pragma unroll
    for (int j = 0; j < 16; ++j)
      acc[j] = fmaf(xv, wT[(size_t)c*COUT + j], acc[j]);
  }

  int m = m0 + ml;
  int n = m / S2, hw = m % S2;
  size_t obase = ((size_t)n*COUT + coh + col)*S2 + hw;
  #pragma unroll
  for (int j = 0; j < 16; ++j) {
    int cl = col + j;
    float f = (float)out3[obase + (size_t)j*S2];
    float p = f > 0.f ? f : avs[cl]*f;
    float t = p*scs[cl] + shs[cl];
    out[obase + (size_t)j*S2] = t + acc[j];
  }
}

extern "C" void kernel_launch(void* const* d_in, const int* in_sizes, int n_in,
                              void* d_out, int out_size, void* d_ws, size_t ws_size,
                              hipStream_t stream) {
  (void)in_sizes; (void)n_in; (void)out_size; (void)ws_size;
  const float* x    = (const float*)d_in[0];
  const float* w1   = (const float*)d_in[1];
  const float* a1   = (const float*)d_in[2];
  const float* g1   = (const float*)d_in[3];
  const float* b1   = (const float*)d_in[4];
  const float* wdw  = (const float*)d_in[5];
  const float* a2   = (const float*)d_in[6];
  const float* g2   = (const float*)d_in[7];
  const float* b2   = (const float*)d_in[8];
  const float* w3   = (const float*)d_in[9];
  const float* a3   = (const float*)d_in[10];
  const float* g3   = (const float*)d_in[11];
  const float* b3   = (const float*)d_in[12];
  const float* wadj = (const float*)d_in[13];
  float* out = (float*)d_out;

  char* ws = (char*)d_ws;
  uint32_t* xbits = (uint32_t*)(ws + OFF_XBITS);
  uint32_t* wb1   = (uint32_t*)(ws + OFF_WB1);
  uint32_t* wb3   = (uint32_t*)(ws + OFF_WB3);
  int8_t*   wdws  = (int8_t*)  (ws + OFF_WDW);
  int*      acc1  = (int*)     (ws + OFF_ACC);
  int*      acc2  = acc1 + 256*4;
  int*      acc3  = acc2 + 256*4;
  int*      thr   = (int*)     (ws + OFF_THR);   // [4][256]: Tp1,Tn1,Tp2,Tn2
  int*      Tp1 = thr, *Tn1 = thr + 256, *Tp2 = thr + 512, *Tn2 = thr + 768;
  float*    wadjT = (float*)   (ws + OFF_WADJT);
  int8_t*   out1  = (int8_t*)  (ws + OFF_OUT1);
  int8_t*   out2  = (int8_t*)  (ws + OFF_OUT2);
  uint32_t* xb2   = (uint32_t*)(ws + OFF_XB2);
  int16_t*  out3  = (int16_t*) (ws + OFF_OUT3);

  hipMemsetAsync(acc1, 0, 3*256*4*sizeof(int), stream);
  packw_kernel<<<256, 64, 0, stream>>>(w1, w3, wdw, wadj, wb1, wb3, wdws, wadjT);
  packx_kernel<<<dim3(NS1/256, 4), 256, 0, stream>>>(x, xbits);
  conv1_kernel<<<dim3(NS1/256, 8), 256, 0, stream>>>(xbits, wb1, out1);
  stats_i8_kernel<<<dim3(256, 8), 256, 0, stream>>>(out1, acc1, S1, 3136);
  thr_kernel<<<1, 256, 0, stream>>>(acc1, a1, g1, b1, 1.f/NS1, -128, 127, Tp1, Tn1);
  dw_kernel<<<NB*COUT, 256, 0, stream>>>(out1, wdws, Tp1, Tn1, out2, acc2);
  thr_kernel<<<1, 256, 0, stream>>>(acc2, a2, g2, b2, 1.f/NS2, -9, 9, Tp2, Tn2);
  pack2_kernel<<<dim3(NS2/256, 8), 256, 0, stream>>>(out2, Tp2, Tn2, xb2);
  conv3_kernel<<<dim3(NS2/256, 8), 256, 0, stream>>>(xb2, wb3, out3);
  stats_i16_kernel<<<dim3(256, 4), 256, 0, stream>>>(out3, acc3, S2, 3136);
  resfinal_kernel<<<dim3(NS2/TILE_M, 2), 512, 0, stream>>>(x, wadjT, out3, a3, g3, b3, acc3, out);
}

// Round 6
// 191.892 us; speedup vs baseline: 1.1992x; 1.1992x over previous
//
#include <hip/hip_runtime.h>
#include <stdint.h>

// ---- problem dims ----
#define NB   32
#define CIN  128
#define COUT 256
#define HH   56
#define WW   56
#define S1   (HH*WW)      // 3136
#define HO   28
#define WO   28
#define S2   (HO*WO)      // 784
#define NS1  (NB*S1)      // 100352
#define NS2  (NB*S2)      // 25088
#define TOT2 (NS2*COUT)   // 6422528
#define EPSV 1e-5f

// ---- workspace layout (bytes) ----
constexpr size_t OFF_XBITS = 0;                                 // NS1*8*4 = 3,211,264
constexpr size_t OFF_WB1   = OFF_XBITS + (size_t)NS1*8*4;       // 8 KB
constexpr size_t OFF_WB3   = OFF_WB1 + 256*8*4;                 // 16 KB
constexpr size_t OFF_WDW   = OFF_WB3 + 256*16*4;                // 4 KB
constexpr size_t OFF_ACC   = OFF_WDW + 4096;                    // 3*256*4 int = 12 KB
constexpr size_t OFF_THR   = OFF_ACC + 3*256*4*sizeof(int);     // 4*256 int = 4 KB
constexpr size_t OFF_WADJT = OFF_THR + 4*256*sizeof(int);       // 128*256*4 = 131,072
constexpr size_t OFF_OUT1  = OFF_WADJT + (size_t)CIN*COUT*4;    // NS1*COUT i8 = 25,690,112
constexpr size_t OFF_OUT2  = OFF_OUT1 + (size_t)NS1*COUT;       // i8 6,422,528
constexpr size_t OFF_XB2   = OFF_OUT2 + (size_t)TOT2;           // NS2*16*4 = 1,605,632
constexpr size_t OFF_OUT3  = OFF_XB2 + (size_t)NS2*16*4;        // i16 12,845,056
// total ~50 MB

// finalize BN scale/shift from exact integer sums of prelu output
__device__ __forceinline__ void bn_finalize(const int* __restrict__ acc4,
                                            float a, float g, float b, float inv_ns,
                                            float& sc, float& sh) {
  float ps = (float)acc4[0];   // sum of v where v>0
  float ng = (float)acc4[1];   // sum of v where v<0
  float pq = (float)acc4[2];   // sum of v^2 where v>0
  float nq = (float)acc4[3];   // sum of v^2 where v<0
  float mean = (ps + a*ng) * inv_ns;
  float ex2  = (pq + a*a*nq) * inv_ns;
  float var  = ex2 - mean*mean;
  float rs   = rsqrtf(var + EPSV);
  sc = rs * g;
  sh = b - mean * sc;
}

// ---------------- pack weights: bitplanes + dw signs + wadj transpose ----------------
__global__ __launch_bounds__(64) void packw_kernel(
    const float* __restrict__ w1, const float* __restrict__ w3,
    const float* __restrict__ wdw, const float* __restrict__ wadj,
    uint32_t* __restrict__ wb1, uint32_t* __restrict__ wb3,
    int8_t* __restrict__ wdws, float* __restrict__ wadjT) {
  int co = blockIdx.x;
  int l  = threadIdx.x;
  for (int h = 0; h < 2; ++h) {
    float v = w1[(size_t)co*CIN + h*64 + l];
    unsigned long long bp = __ballot(v > 0.f);
    unsigned long long bn = __ballot(v < 0.f);
    if (l == 0) {
      wb1[co*8 + 2*h    ] = (uint32_t)bp;
      wb1[co*8 + 2*h + 1] = (uint32_t)(bp >> 32);
      wb1[co*8 + 4 + 2*h    ] = (uint32_t)bn;
      wb1[co*8 + 4 + 2*h + 1] = (uint32_t)(bn >> 32);
    }
  }
  for (int h = 0; h < 4; ++h) {
    float v = w3[(size_t)co*COUT + h*64 + l];
    unsigned long long bp = __ballot(v > 0.f);
    unsigned long long bn = __ballot(v < 0.f);
    if (l == 0) {
      wb3[co*16 + 2*h    ] = (uint32_t)bp;
      wb3[co*16 + 2*h + 1] = (uint32_t)(bp >> 32);
      wb3[co*16 + 8 + 2*h    ] = (uint32_t)bn;
      wb3[co*16 + 8 + 2*h + 1] = (uint32_t)(bn >> 32);
    }
  }
  if (l < 9) {
    float v = wdw[co*9 + l];
    wdws[co*9 + l] = (int8_t)((v > 0.f) - (v < 0.f));
  }
  // transpose w_adj: wadjT[c][co] = wadj[co][c]
  #pragma unroll
  for (int k = 0; k < 2; ++k) {
    int c = 2*l + k;
    wadjT[(size_t)c*COUT + co] = wadj[(size_t)co*CIN + c];
  }
}

// ---------------- pack x into bitplanes over C (split over wdx) ----------------
__global__ __launch_bounds__(256) void packx_kernel(
    const float* __restrict__ x, uint32_t* __restrict__ xbits) {
  int m = blockIdx.x*256 + threadIdx.x;     // m = n*S1 + hw
  int wdx = blockIdx.y;                     // 0..3
  int n = m / S1, hw = m % S1;
  size_t base = ((size_t)n*CIN + wdx*32)*S1 + hw;
  uint32_t p = 0, q = 0;
  #pragma unroll
  for (int j = 0; j < 32; ++j) {
    float v = x[base + (size_t)j*S1];
    p |= (uint32_t)(v > 0.f) << j;
    q |= (uint32_t)(v < 0.f) << j;
  }
  xbits[(size_t)m*8 + wdx    ] = p;
  xbits[(size_t)m*8 + 4 + wdx] = q;
}

// ---------------- conv1: binary 1x1 via bitplane popcount ----------------
__global__ __launch_bounds__(256) void conv1_kernel(
    const uint32_t* __restrict__ xb, const uint32_t* __restrict__ wb,
    int8_t* __restrict__ out1) {
  int m = blockIdx.x*256 + threadIdx.x;
  int n = m / S1, hw = m % S1;
  const uint32_t* xw = xb + (size_t)m*8;
  uint32_t p0 = xw[0], p1 = xw[1], p2 = xw[2], p3 = xw[3];
  uint32_t q0 = xw[4], q1 = xw[5], q2 = xw[6], q3 = xw[7];
  int co0 = blockIdx.y * 32;
  size_t obase = ((size_t)n*COUT)*S1 + hw;
  #pragma unroll 4
  for (int co = co0; co < co0 + 32; ++co) {
    const uint32_t* w8 = wb + (size_t)co*8;
    uint32_t a0 = w8[0], a1 = w8[1], a2 = w8[2], a3 = w8[3];
    uint32_t b0 = w8[4], b1 = w8[5], b2 = w8[6], b3 = w8[7];
    int acc = __popc(p0&a0) + __popc(p1&a1) + __popc(p2&a2) + __popc(p3&a3)
            + __popc(q0&b0) + __popc(q1&b1) + __popc(q2&b2) + __popc(q3&b3)
            - __popc(p0&b0) - __popc(p1&b1) - __popc(p2&b2) - __popc(p3&b3)
            - __popc(q0&a0) - __popc(q1&a1) - __popc(q2&a2) - __popc(q3&a3);
    if (acc > 127) acc = 127;   // +128 would wrap int8; prob ~2^-128
    out1[obase + (size_t)co*S1] = (int8_t)acc;
  }
}

// ---------------- per-channel integer stats (int8 buffer) ----------------
__global__ __launch_bounds__(256) void stats_i8_kernel(
    const int8_t* __restrict__ buf, int* __restrict__ accum,
    int s_sp, int quads_per_block) {
  int co = blockIdx.x, slice = blockIdx.y;
  int q0 = slice * quads_per_block;
  int psum = 0, nsum = 0, psq = 0, nsq = 0;
  for (int i = threadIdx.x; i < quads_per_block; i += 256) {
    int flat = (q0 + i) * 4;
    int n = flat / s_sp, hw = flat % s_sp;
    char4 v = *reinterpret_cast<const char4*>(buf + (size_t)(n*COUT + co)*s_sp + hw);
    int vs[4] = {v.x, v.y, v.z, v.w};
    #pragma unroll
    for (int k = 0; k < 4; ++k) {
      int f = vs[k];
      if (f > 0) { psum += f; psq += f*f; } else { nsum += f; nsq += f*f; }
    }
  }
  __shared__ int r0[256], r1[256], r2[256], r3[256];
  int t = threadIdx.x;
  r0[t] = psum; r1[t] = nsum; r2[t] = psq; r3[t] = nsq;
  __syncthreads();
  for (int s = 128; s > 0; s >>= 1) {
    if (t < s) { r0[t]+=r0[t+s]; r1[t]+=r1[t+s]; r2[t]+=r2[t+s]; r3[t]+=r3[t+s]; }
    __syncthreads();
  }
  if (t == 0) {
    atomicAdd(&accum[co*4+0], r0[0]);
    atomicAdd(&accum[co*4+1], r1[0]);
    atomicAdd(&accum[co*4+2], r2[0]);
    atomicAdd(&accum[co*4+3], r3[0]);
  }
}

__global__ __launch_bounds__(256) void stats_i16_kernel(
    const int16_t* __restrict__ buf, int* __restrict__ accum,
    int s_sp, int pairs_per_block) {
  int co = blockIdx.x, slice = blockIdx.y;
  int p0i = slice * pairs_per_block;
  int psum = 0, nsum = 0, psq = 0, nsq = 0;
  for (int i = threadIdx.x; i < pairs_per_block; i += 256) {
    int flat = (p0i + i) * 2;
    int n = flat / s_sp, hw = flat % s_sp;
    short2 v = *reinterpret_cast<const short2*>(buf + (size_t)(n*COUT + co)*s_sp + hw);
    int vs[2] = {v.x, v.y};
    #pragma unroll
    for (int k = 0; k < 2; ++k) {
      int f = vs[k];
      if (f > 0) { psum += f; psq += f*f; } else { nsum += f; nsq += f*f; }
    }
  }
  __shared__ int r0[256], r1[256], r2[256], r3[256];
  int t = threadIdx.x;
  r0[t] = psum; r1[t] = nsum; r2[t] = psq; r3[t] = nsq;
  __syncthreads();
  for (int s = 128; s > 0; s >>= 1) {
    if (t < s) { r0[t]+=r0[t+s]; r1[t]+=r1[t+s]; r2[t]+=r2[t+s]; r3[t]+=r3[t+s]; }
    __syncthreads();
  }
  if (t == 0) {
    atomicAdd(&accum[co*4+0], r0[0]);
    atomicAdd(&accum[co*4+1], r1[0]);
    atomicAdd(&accum[co*4+2], r2[0]);
    atomicAdd(&accum[co*4+3], r3[0]);
  }
}

// ---------------- thresholds: sign(BN(prelu(v))) == (v>=Tpos) - (v<=Tneg) ----------------
// exact: evaluates the identical float expression at every integer v in range.
// valid because tv is monotone nondecreasing in v (a>0, sc>0 for this problem).
__global__ __launch_bounds__(256) void thr_kernel(
    const int* __restrict__ accum, const float* __restrict__ a,
    const float* __restrict__ g, const float* __restrict__ b,
    float inv_ns, int vlo, int vhi,
    int* __restrict__ Tpos, int* __restrict__ Tneg) {
  int co = threadIdx.x;
  float av = a[co], sc, sh;
  bn_finalize(accum + co*4, av, g[co], b[co], inv_ns, sc, sh);
  int tp = vhi + 1, tn = vlo - 1;
  for (int v = vlo; v <= vhi; ++v) {
    float f = (float)v;
    float p = f > 0.f ? f : av*f;
    float tv = p*sc + sh;
    if (tv > 0.f && v < tp) tp = v;    // min v with tv>0
    if (tv < 0.f && v > tn) tn = v;    // max v with tv<0
  }
  Tpos[co] = tp;
  Tneg[co] = tn;
}

// ---------------- depthwise 3x3 s2 p1 via thresholds, register sliding window ----------------
// one thread per output ROW (n,co,ho): 3 input rows as aligned dwords, signs in regs,
// 2 outputs per step with carry column, 7 packed dword stores.
__device__ __forceinline__ int thr_sgn(uint32_t d, int k, int Tp, int Tn) {
  int v = (int)(int8_t)(d >> (8*k));
  return (v >= Tp) - (v <= Tn);
}

__global__ __launch_bounds__(256) void dw_kernel(
    const int8_t* __restrict__ out1, const int8_t* __restrict__ wdws,
    const int* __restrict__ Tp1, const int* __restrict__ Tn1,
    int8_t* __restrict__ out2) {
  int idx = blockIdx.x*256 + threadIdx.x;   // over NB*COUT*HO = 229376
  int ho = idx % HO;
  int nc = idx / HO;                        // n*COUT + co
  int co = nc & (COUT-1);
  int Tp = Tp1[co], Tn = Tn1[co];

  int wv[9];
  #pragma unroll
  for (int k = 0; k < 9; ++k) wv[k] = wdws[co*9 + k];

  const int8_t* base = out1 + (size_t)nc * S1;
  const uint32_t* row0 = (const uint32_t*)(base + (2*ho - 1)*WW);
  const uint32_t* row1 = (const uint32_t*)(base + (2*ho    )*WW);
  const uint32_t* row2 = (const uint32_t*)(base + (2*ho + 1)*WW);
  bool v0 = (ho > 0);
  int m0 = v0 ? -1 : 0;    // sign mask for top pad row (pad applied AFTER sign -> 0)

  uint32_t* o32 = (uint32_t*)(out2 + (size_t)nc*S2 + ho*WO);

  int c0 = 0, c1 = 0, c2 = 0;   // carry: sign at col 4q-1 (left pad -> 0)
  uint32_t obuf = 0;
  #pragma unroll
  for (int q = 0; q < 14; ++q) {
    uint32_t d0 = v0 ? row0[q] : 0u;
    uint32_t d1 = row1[q];
    uint32_t d2 = row2[q];
    int s00 = thr_sgn(d0,0,Tp,Tn) & m0, s01 = thr_sgn(d0,1,Tp,Tn) & m0,
        s02 = thr_sgn(d0,2,Tp,Tn) & m0, s03 = thr_sgn(d0,3,Tp,Tn) & m0;
    int s10 = thr_sgn(d1,0,Tp,Tn), s11 = thr_sgn(d1,1,Tp,Tn),
        s12 = thr_sgn(d1,2,Tp,Tn), s13 = thr_sgn(d1,3,Tp,Tn);
    int s20 = thr_sgn(d2,0,Tp,Tn), s21 = thr_sgn(d2,1,Tp,Tn),
        s22 = thr_sgn(d2,2,Tp,Tn), s23 = thr_sgn(d2,3,Tp,Tn);
    // output wo=2q: cols 4q-1,4q,4q+1 ; wo=2q+1: cols 4q+1,4q+2,4q+3
    int a0 = c0*wv[0] + s00*wv[1] + s01*wv[2]
           + c1*wv[3] + s10*wv[4] + s11*wv[5]
           + c2*wv[6] + s20*wv[7] + s21*wv[8];
    int a1 = s01*wv[0] + s02*wv[1] + s03*wv[2]
           + s11*wv[3] + s12*wv[4] + s13*wv[5]
           + s21*wv[6] + s22*wv[7] + s23*wv[8];
    c0 = s03; c1 = s13; c2 = s23;
    if ((q & 1) == 0) {
      obuf = (uint32_t)(a0 & 0xff) | ((uint32_t)(a1 & 0xff) << 8);
    } else {
      obuf |= ((uint32_t)(a0 & 0xff) << 16) | ((uint32_t)(a1 & 0xff) << 24);
      o32[q >> 1] = obuf;
    }
  }
}

// ---------------- pack sign(BN2(prelu(out2))) via thresholds, split over wdx ----------------
__global__ __launch_bounds__(256) void pack2_kernel(
    const int8_t* __restrict__ out2,
    const int* __restrict__ Tp2, const int* __restrict__ Tn2,
    uint32_t* __restrict__ xb2) {
  int m = blockIdx.x*256 + threadIdx.x;   // n*S2 + hw
  int wdx = blockIdx.y;                   // 0..7
  int n = m / S2, hw = m % S2;
  uint32_t p = 0, q = 0;
  #pragma unroll
  for (int j = 0; j < 32; ++j) {
    int c = wdx*32 + j;
    int v = out2[(size_t)(n*COUT + c)*S2 + hw];
    p |= (uint32_t)(v >= Tp2[c]) << j;
    q |= (uint32_t)(v <= Tn2[c]) << j;
  }
  xb2[(size_t)m*16 + wdx    ] = p;
  xb2[(size_t)m*16 + 8 + wdx] = q;
}

// ---------------- conv3: binary 1x1 256->256 ----------------
__global__ __launch_bounds__(256) void conv3_kernel(
    const uint32_t* __restrict__ xb2, const uint32_t* __restrict__ wb3,
    int16_t* __restrict__ out3) {
  int m = blockIdx.x*256 + threadIdx.x;   // NS2
  int n = m / S2, hw = m % S2;
  const uint32_t* xw = xb2 + (size_t)m*16;
  uint32_t P[8], Q[8];
  #pragma unroll
  for (int i = 0; i < 8; ++i) { P[i] = xw[i]; Q[i] = xw[8+i]; }
  int co0 = blockIdx.y * 32;
  size_t obase = ((size_t)n*COUT)*S2 + hw;
  #pragma unroll 2
  for (int co = co0; co < co0 + 32; ++co) {
    const uint32_t* w = wb3 + (size_t)co*16;
    int acc = 0;
    #pragma unroll
    for (int i = 0; i < 8; ++i) {
      uint32_t wp = w[i], wn = w[8+i];
      acc += __popc(P[i]&wp) + __popc(Q[i]&wn) - __popc(P[i]&wn) - __popc(Q[i]&wp);
    }
    out3[obase + (size_t)co*S2] = (int16_t)acc;
  }
}

// ---------------- fused residual (fp32 1x1 s2) + BN3(prelu(out3)) + add ----------------
#define TILE_M 64
__global__ __launch_bounds__(512, 2) void resfinal_kernel(
    const float* __restrict__ x, const float* __restrict__ wadjT,
    const int16_t* __restrict__ out3,
    const float* __restrict__ a3, const float* __restrict__ g3,
    const float* __restrict__ b3, const int* __restrict__ acc3,
    float* __restrict__ out) {
  __shared__ float xt[CIN][TILE_M];                 // 32 KB
  __shared__ float scs[128], shs[128], avs[128];    // 1.5 KB
  int tid = threadIdx.x;
  int m0 = blockIdx.x * TILE_M;
  int coh = blockIdx.y * 128;

  if (tid < 128) {
    int co = coh + tid;
    float sc, sh;
    bn_finalize(acc3 + co*4, a3[co], g3[co], b3[co], 1.f/NS2, sc, sh);
    scs[tid] = sc; shs[tid] = sh; avs[tid] = a3[co];
  }
  #pragma unroll
  for (int k = 0; k < 16; ++k) {
    int idx = k*512 + tid;
    int c  = idx >> 6;
    int ml = idx & 63;
    int m = m0 + ml;
    int n = m / S2, hw = m % S2;
    int ho = hw / WO, wo = hw % WO;
    xt[c][ml] = x[((size_t)n*CIN + c)*S1 + (size_t)(2*ho)*WW + 2*wo];
  }
  __syncthreads();

  int ml  = tid & 63;
  int cg  = __builtin_amdgcn_readfirstlane(tid >> 6);  // wave-uniform 0..7
  int col = cg * 16;
  const float* wT = wadjT + coh + col;

  float acc[16];
  #pragma unroll
  for (int j = 0; j < 16; ++j) acc[j] = 0.f;

  #pragma unroll 2
  for (int c = 0; c < CIN; ++c) {
    float xv = xt[c][ml];
    #pragma unroll
    for (int j = 0; j < 16; ++j)
      acc[j] = fmaf(xv, wT[(size_t)c*COUT + j], acc[j]);
  }

  int m = m0 + ml;
  int n = m / S2, hw = m % S2;
  size_t obase = ((size_t)n*COUT + coh + col)*S2 + hw;
  #pragma unroll
  for (int j = 0; j < 16; ++j) {
    int cl = col + j;
    float f = (float)out3[obase + (size_t)j*S2];
    float p = f > 0.f ? f : avs[cl]*f;
    float t = p*scs[cl] + shs[cl];
    out[obase + (size_t)j*S2] = t + acc[j];
  }
}

extern "C" void kernel_launch(void* const* d_in, const int* in_sizes, int n_in,
                              void* d_out, int out_size, void* d_ws, size_t ws_size,
                              hipStream_t stream) {
  (void)in_sizes; (void)n_in; (void)out_size; (void)ws_size;
  const float* x    = (const float*)d_in[0];
  const float* w1   = (const float*)d_in[1];
  const float* a1   = (const float*)d_in[2];
  const float* g1   = (const float*)d_in[3];
  const float* b1   = (const float*)d_in[4];
  const float* wdw  = (const float*)d_in[5];
  const float* a2   = (const float*)d_in[6];
  const float* g2   = (const float*)d_in[7];
  const float* b2   = (const float*)d_in[8];
  const float* w3   = (const float*)d_in[9];
  const float* a3   = (const float*)d_in[10];
  const float* g3   = (const float*)d_in[11];
  const float* b3   = (const float*)d_in[12];
  const float* wadj = (const float*)d_in[13];
  float* out = (float*)d_out;

  char* ws = (char*)d_ws;
  uint32_t* xbits = (uint32_t*)(ws + OFF_XBITS);
  uint32_t* wb1   = (uint32_t*)(ws + OFF_WB1);
  uint32_t* wb3   = (uint32_t*)(ws + OFF_WB3);
  int8_t*   wdws  = (int8_t*)  (ws + OFF_WDW);
  int*      acc1  = (int*)     (ws + OFF_ACC);
  int*      acc2  = acc1 + 256*4;
  int*      acc3  = acc2 + 256*4;
  int*      thr   = (int*)     (ws + OFF_THR);   // [4][256]: Tp1,Tn1,Tp2,Tn2
  int*      Tp1 = thr, *Tn1 = thr + 256, *Tp2 = thr + 512, *Tn2 = thr + 768;
  float*    wadjT = (float*)   (ws + OFF_WADJT);
  int8_t*   out1  = (int8_t*)  (ws + OFF_OUT1);
  int8_t*   out2  = (int8_t*)  (ws + OFF_OUT2);
  uint32_t* xb2   = (uint32_t*)(ws + OFF_XB2);
  int16_t*  out3  = (int16_t*) (ws + OFF_OUT3);

  hipMemsetAsync(acc1, 0, 3*256*4*sizeof(int), stream);
  packw_kernel<<<256, 64, 0, stream>>>(w1, w3, wdw, wadj, wb1, wb3, wdws, wadjT);
  packx_kernel<<<dim3(NS1/256, 4), 256, 0, stream>>>(x, xbits);
  conv1_kernel<<<dim3(NS1/256, 8), 256, 0, stream>>>(xbits, wb1, out1);
  stats_i8_kernel<<<dim3(256, 8), 256, 0, stream>>>(out1, acc1, S1, 3136);
  thr_kernel<<<1, 256, 0, stream>>>(acc1, a1, g1, b1, 1.f/NS1, -128, 127, Tp1, Tn1);
  dw_kernel<<<NB*COUT*HO/256, 256, 0, stream>>>(out1, wdws, Tp1, Tn1, out2);
  stats_i8_kernel<<<dim3(256, 4), 256, 0, stream>>>(out2, acc2, S2, 1568);
  thr_kernel<<<1, 256, 0, stream>>>(acc2, a2, g2, b2, 1.f/NS2, -9, 9, Tp2, Tn2);
  pack2_kernel<<<dim3(NS2/256, 8), 256, 0, stream>>>(out2, Tp2, Tn2, xb2);
  conv3_kernel<<<dim3(NS2/256, 8), 256, 0, stream>>>(xb2, wb3, out3);
  stats_i16_kernel<<<dim3(256, 4), 256, 0, stream>>>(out3, acc3, S2, 3136);
  resfinal_kernel<<<dim3(NS2/TILE_M, 2), 512, 0, stream>>>(x, wadjT, out3, a3, g3, b3, acc3, out);
}

// Round 7
// 180.273 us; speedup vs baseline: 1.2765x; 1.0644x over previous
//
#include <hip/hip_runtime.h>
#include <stdint.h>

// ---- problem dims ----
#define NB   32
#define CIN  128
#define COUT 256
#define HH   56
#define WW   56
#define S1   (HH*WW)      // 3136
#define HO   28
#define WO   28
#define S2   (HO*WO)      // 784
#define NS1  (NB*S1)      // 100352
#define NS2  (NB*S2)      // 25088
#define TOT2 (NS2*COUT)   // 6422528
#define EPSV 1e-5f

// ---- workspace layout (bytes) ----
constexpr size_t OFF_XBITS = 0;                                 // NS1*8*4 = 3,211,264
constexpr size_t OFF_WB1   = OFF_XBITS + (size_t)NS1*8*4;       // 8 KB
constexpr size_t OFF_WB3   = OFF_WB1 + 256*8*4;                 // 16 KB
constexpr size_t OFF_WDW   = OFF_WB3 + 256*16*4;                // 4 KB
constexpr size_t OFF_ACC   = OFF_WDW + 4096;                    // 12 KB
constexpr size_t OFF_THR   = OFF_ACC + 3*256*4*sizeof(int);     // 4 KB
constexpr size_t OFF_WBADJ = OFF_THR + 4*256*sizeof(int);       // 256*128*2 = 65,536
constexpr size_t OFF_XG    = OFF_WBADJ + (size_t)COUT*CIN*2;    // NS2*128*2 = 6,422,528
constexpr size_t OFF_OUT1  = OFF_XG + (size_t)NS2*CIN*2;        // NS1*COUT i8 = 25,690,112
constexpr size_t OFF_OUT2  = OFF_OUT1 + (size_t)NS1*COUT;       // i8 6,422,528
constexpr size_t OFF_XB2   = OFF_OUT2 + (size_t)TOT2;           // NS2*16*4 = 1,605,632
constexpr size_t OFF_OUT3  = OFF_XB2 + (size_t)NS2*16*4;        // i16 12,845,056
// total ~56 MB

typedef __attribute__((ext_vector_type(8))) short bf16x8;
typedef __attribute__((ext_vector_type(4))) float f32x4;

__device__ __forceinline__ uint32_t f2bf(float v) {
  uint32_t u = __float_as_uint(v);
  return (u + 0x7fffu + ((u >> 16) & 1u)) >> 16;   // RNE bf16 bits
}

// finalize BN scale/shift from exact integer sums of prelu output
__device__ __forceinline__ void bn_finalize(const int* __restrict__ acc4,
                                            float a, float g, float b, float inv_ns,
                                            float& sc, float& sh) {
  float ps = (float)acc4[0];   // sum of v where v>0
  float ng = (float)acc4[1];   // sum of v where v<0
  float pq = (float)acc4[2];   // sum of v^2 where v>0
  float nq = (float)acc4[3];   // sum of v^2 where v<0
  float mean = (ps + a*ng) * inv_ns;
  float ex2  = (pq + a*a*nq) * inv_ns;
  float var  = ex2 - mean*mean;
  float rs   = rsqrtf(var + EPSV);
  sc = rs * g;
  sh = b - mean * sc;
}

// ---------------- pack weights: bitplanes + dw signs + bf16 w_adj ----------------
__global__ __launch_bounds__(64) void packw_kernel(
    const float* __restrict__ w1, const float* __restrict__ w3,
    const float* __restrict__ wdw, const float* __restrict__ wadj,
    uint32_t* __restrict__ wb1, uint32_t* __restrict__ wb3,
    int8_t* __restrict__ wdws, uint32_t* __restrict__ wbadj) {
  int co = blockIdx.x;
  int l  = threadIdx.x;
  for (int h = 0; h < 2; ++h) {
    float v = w1[(size_t)co*CIN + h*64 + l];
    unsigned long long bp = __ballot(v > 0.f);
    unsigned long long bn = __ballot(v < 0.f);
    if (l == 0) {
      wb1[co*8 + 2*h    ] = (uint32_t)bp;
      wb1[co*8 + 2*h + 1] = (uint32_t)(bp >> 32);
      wb1[co*8 + 4 + 2*h    ] = (uint32_t)bn;
      wb1[co*8 + 4 + 2*h + 1] = (uint32_t)(bn >> 32);
    }
  }
  for (int h = 0; h < 4; ++h) {
    float v = w3[(size_t)co*COUT + h*64 + l];
    unsigned long long bp = __ballot(v > 0.f);
    unsigned long long bn = __ballot(v < 0.f);
    if (l == 0) {
      wb3[co*16 + 2*h    ] = (uint32_t)bp;
      wb3[co*16 + 2*h + 1] = (uint32_t)(bp >> 32);
      wb3[co*16 + 8 + 2*h    ] = (uint32_t)bn;
      wb3[co*16 + 8 + 2*h + 1] = (uint32_t)(bn >> 32);
    }
  }
  if (l < 9) {
    float v = wdw[co*9 + l];
    wdws[co*9 + l] = (int8_t)((v > 0.f) - (v < 0.f));
  }
  // bf16 w_adj, layout [co][c], packed 2 per dword
  {
    float v0 = wadj[(size_t)co*CIN + 2*l];
    float v1 = wadj[(size_t)co*CIN + 2*l + 1];
    wbadj[co*64 + l] = f2bf(v0) | (f2bf(v1) << 16);
  }
}

// ---------------- pack x into bitplanes + bf16 compact stride-2 tile ----------------
__global__ __launch_bounds__(256) void packx_kernel(
    const float* __restrict__ x, uint32_t* __restrict__ xbits,
    uint32_t* __restrict__ xg) {
  int m = blockIdx.x*256 + threadIdx.x;     // m = n*S1 + hw
  int wdx = blockIdx.y;                     // 0..3
  int n = m / S1, hw = m % S1;
  size_t base = ((size_t)n*CIN + wdx*32)*S1 + hw;
  uint32_t p = 0, q = 0;
  uint32_t bv[16];
  #pragma unroll
  for (int j = 0; j < 32; ++j) {
    float v = x[base + (size_t)j*S1];
    p |= (uint32_t)(v > 0.f) << j;
    q |= (uint32_t)(v < 0.f) << j;
    uint32_t b = f2bf(v);
    if (j & 1) bv[j >> 1] |= b << 16; else bv[j >> 1] = b;
  }
  xbits[(size_t)m*8 + wdx    ] = p;
  xbits[(size_t)m*8 + 4 + wdx] = q;
  int h = hw / WW, w = hw % WW;
  if (((h | w) & 1) == 0) {
    int m2 = n*S2 + (h >> 1)*WO + (w >> 1);
    uint4* dst = (uint4*)(xg + (size_t)m2*64 + wdx*16);
    dst[0] = make_uint4(bv[0],  bv[1],  bv[2],  bv[3]);
    dst[1] = make_uint4(bv[4],  bv[5],  bv[6],  bv[7]);
    dst[2] = make_uint4(bv[8],  bv[9],  bv[10], bv[11]);
    dst[3] = make_uint4(bv[12], bv[13], bv[14], bv[15]);
  }
}

// ---------------- conv1: binary 1x1 via bitplane popcount ----------------
__global__ __launch_bounds__(256) void conv1_kernel(
    const uint32_t* __restrict__ xb, const uint32_t* __restrict__ wb,
    int8_t* __restrict__ out1) {
  int m = blockIdx.x*256 + threadIdx.x;
  int n = m / S1, hw = m % S1;
  const uint32_t* xw = xb + (size_t)m*8;
  uint32_t p0 = xw[0], p1 = xw[1], p2 = xw[2], p3 = xw[3];
  uint32_t q0 = xw[4], q1 = xw[5], q2 = xw[6], q3 = xw[7];
  int co0 = blockIdx.y * 32;
  size_t obase = ((size_t)n*COUT)*S1 + hw;
  #pragma unroll 4
  for (int co = co0; co < co0 + 32; ++co) {
    const uint32_t* w8 = wb + (size_t)co*8;
    uint32_t a0 = w8[0], a1 = w8[1], a2 = w8[2], a3 = w8[3];
    uint32_t b0 = w8[4], b1 = w8[5], b2 = w8[6], b3 = w8[7];
    int acc = __popc(p0&a0) + __popc(p1&a1) + __popc(p2&a2) + __popc(p3&a3)
            + __popc(q0&b0) + __popc(q1&b1) + __popc(q2&b2) + __popc(q3&b3)
            - __popc(p0&b0) - __popc(p1&b1) - __popc(p2&b2) - __popc(p3&b3)
            - __popc(q0&a0) - __popc(q1&a1) - __popc(q2&a2) - __popc(q3&a3);
    if (acc > 127) acc = 127;   // +128 would wrap int8; prob ~2^-128
    out1[obase + (size_t)co*S1] = (int8_t)acc;
  }
}

// ---------------- per-channel integer stats (int8 buffer) ----------------
__global__ __launch_bounds__(256) void stats_i8_kernel(
    const int8_t* __restrict__ buf, int* __restrict__ accum,
    int s_sp, int quads_per_block) {
  int co = blockIdx.x, slice = blockIdx.y;
  int q0 = slice * quads_per_block;
  int psum = 0, nsum = 0, psq = 0, nsq = 0;
  for (int i = threadIdx.x; i < quads_per_block; i += 256) {
    int flat = (q0 + i) * 4;
    int n = flat / s_sp, hw = flat % s_sp;
    char4 v = *reinterpret_cast<const char4*>(buf + (size_t)(n*COUT + co)*s_sp + hw);
    int vs[4] = {v.x, v.y, v.z, v.w};
    #pragma unroll
    for (int k = 0; k < 4; ++k) {
      int f = vs[k];
      if (f > 0) { psum += f; psq += f*f; } else { nsum += f; nsq += f*f; }
    }
  }
  __shared__ int r0[256], r1[256], r2[256], r3[256];
  int t = threadIdx.x;
  r0[t] = psum; r1[t] = nsum; r2[t] = psq; r3[t] = nsq;
  __syncthreads();
  for (int s = 128; s > 0; s >>= 1) {
    if (t < s) { r0[t]+=r0[t+s]; r1[t]+=r1[t+s]; r2[t]+=r2[t+s]; r3[t]+=r3[t+s]; }
    __syncthreads();
  }
  if (t == 0) {
    atomicAdd(&accum[co*4+0], r0[0]);
    atomicAdd(&accum[co*4+1], r1[0]);
    atomicAdd(&accum[co*4+2], r2[0]);
    atomicAdd(&accum[co*4+3], r3[0]);
  }
}

__global__ __launch_bounds__(256) void stats_i16_kernel(
    const int16_t* __restrict__ buf, int* __restrict__ accum,
    int s_sp, int pairs_per_block) {
  int co = blockIdx.x, slice = blockIdx.y;
  int p0i = slice * pairs_per_block;
  int psum = 0, nsum = 0, psq = 0, nsq = 0;
  for (int i = threadIdx.x; i < pairs_per_block; i += 256) {
    int flat = (p0i + i) * 2;
    int n = flat / s_sp, hw = flat % s_sp;
    short2 v = *reinterpret_cast<const short2*>(buf + (size_t)(n*COUT + co)*s_sp + hw);
    int vs[2] = {v.x, v.y};
    #pragma unroll
    for (int k = 0; k < 2; ++k) {
      int f = vs[k];
      if (f > 0) { psum += f; psq += f*f; } else { nsum += f; nsq += f*f; }
    }
  }
  __shared__ int r0[256], r1[256], r2[256], r3[256];
  int t = threadIdx.x;
  r0[t] = psum; r1[t] = nsum; r2[t] = psq; r3[t] = nsq;
  __syncthreads();
  for (int s = 128; s > 0; s >>= 1) {
    if (t < s) { r0[t]+=r0[t+s]; r1[t]+=r1[t+s]; r2[t]+=r2[t+s]; r3[t]+=r3[t+s]; }
    __syncthreads();
  }
  if (t == 0) {
    atomicAdd(&accum[co*4+0], r0[0]);
    atomicAdd(&accum[co*4+1], r1[0]);
    atomicAdd(&accum[co*4+2], r2[0]);
    atomicAdd(&accum[co*4+3], r3[0]);
  }
}

// ---------------- thresholds: sign(BN(prelu(v))) == (v>=Tpos) - (v<=Tneg) ----------------
__global__ __launch_bounds__(256) void thr_kernel(
    const int* __restrict__ accum, const float* __restrict__ a,
    const float* __restrict__ g, const float* __restrict__ b,
    float inv_ns, int vlo, int vhi,
    int* __restrict__ Tpos, int* __restrict__ Tneg) {
  int co = threadIdx.x;
  float av = a[co], sc, sh;
  bn_finalize(accum + co*4, av, g[co], b[co], inv_ns, sc, sh);
  int tp = vhi + 1, tn = vlo - 1;
  for (int v = vlo; v <= vhi; ++v) {
    float f = (float)v;
    float p = f > 0.f ? f : av*f;
    float tv = p*sc + sh;
    if (tv > 0.f && v < tp) tp = v;    // min v with tv>0
    if (tv < 0.f && v > tn) tn = v;    // max v with tv<0
  }
  Tpos[co] = tp;
  Tneg[co] = tn;
}

// ---------------- depthwise 3x3 s2 p1 via thresholds, register sliding window ----------------
__device__ __forceinline__ int thr_sgn(uint32_t d, int k, int Tp, int Tn) {
  int v = (int)(int8_t)(d >> (8*k));
  return (v >= Tp) - (v <= Tn);
}

__global__ __launch_bounds__(256) void dw_kernel(
    const int8_t* __restrict__ out1, const int8_t* __restrict__ wdws,
    const int* __restrict__ Tp1, const int* __restrict__ Tn1,
    int8_t* __restrict__ out2) {
  int idx = blockIdx.x*256 + threadIdx.x;   // over NB*COUT*HO = 229376
  int ho = idx % HO;
  int nc = idx / HO;                        // n*COUT + co
  int co = nc & (COUT-1);
  int Tp = Tp1[co], Tn = Tn1[co];

  int wv[9];
  #pragma unroll
  for (int k = 0; k < 9; ++k) wv[k] = wdws[co*9 + k];

  const int8_t* base = out1 + (size_t)nc * S1;
  const uint32_t* row0 = (const uint32_t*)(base + (2*ho - 1)*WW);
  const uint32_t* row1 = (const uint32_t*)(base + (2*ho    )*WW);
  const uint32_t* row2 = (const uint32_t*)(base + (2*ho + 1)*WW);
  bool v0 = (ho > 0);
  int m0 = v0 ? -1 : 0;    // sign mask for top pad row (pad applied AFTER sign -> 0)

  uint32_t* o32 = (uint32_t*)(out2 + (size_t)nc*S2 + ho*WO);

  int c0 = 0, c1 = 0, c2 = 0;   // carry: sign at col 4q-1 (left pad -> 0)
  uint32_t obuf = 0;
  #pragma unroll
  for (int q = 0; q < 14; ++q) {
    uint32_t d0 = v0 ? row0[q] : 0u;
    uint32_t d1 = row1[q];
    uint32_t d2 = row2[q];
    int s00 = thr_sgn(d0,0,Tp,Tn) & m0, s01 = thr_sgn(d0,1,Tp,Tn) & m0,
        s02 = thr_sgn(d0,2,Tp,Tn) & m0, s03 = thr_sgn(d0,3,Tp,Tn) & m0;
    int s10 = thr_sgn(d1,0,Tp,Tn), s11 = thr_sgn(d1,1,Tp,Tn),
        s12 = thr_sgn(d1,2,Tp,Tn), s13 = thr_sgn(d1,3,Tp,Tn);
    int s20 = thr_sgn(d2,0,Tp,Tn), s21 = thr_sgn(d2,1,Tp,Tn),
        s22 = thr_sgn(d2,2,Tp,Tn), s23 = thr_sgn(d2,3,Tp,Tn);
    int a0 = c0*wv[0] + s00*wv[1] + s01*wv[2]
           + c1*wv[3] + s10*wv[4] + s11*wv[5]
           + c2*wv[6] + s20*wv[7] + s21*wv[8];
    int a1 = s01*wv[0] + s02*wv[1] + s03*wv[2]
           + s11*wv[3] + s12*wv[4] + s13*wv[5]
           + s21*wv[6] + s22*wv[7] + s23*wv[8];
    c0 = s03; c1 = s13; c2 = s23;
    if ((q & 1) == 0) {
      obuf = (uint32_t)(a0 & 0xff) | ((uint32_t)(a1 & 0xff) << 8);
    } else {
      obuf |= ((uint32_t)(a0 & 0xff) << 16) | ((uint32_t)(a1 & 0xff) << 24);
      o32[q >> 1] = obuf;
    }
  }
}

// ---------------- pack sign(BN2(prelu(out2))) via thresholds, split over wdx ----------------
__global__ __launch_bounds__(256) void pack2_kernel(
    const int8_t* __restrict__ out2,
    const int* __restrict__ Tp2, const int* __restrict__ Tn2,
    uint32_t* __restrict__ xb2) {
  int m = blockIdx.x*256 + threadIdx.x;   // n*S2 + hw
  int wdx = blockIdx.y;                   // 0..7
  int n = m / S2, hw = m % S2;
  uint32_t p = 0, q = 0;
  #pragma unroll
  for (int j = 0; j < 32; ++j) {
    int c = wdx*32 + j;
    int v = out2[(size_t)(n*COUT + c)*S2 + hw];
    p |= (uint32_t)(v >= Tp2[c]) << j;
    q |= (uint32_t)(v <= Tn2[c]) << j;
  }
  xb2[(size_t)m*16 + wdx    ] = p;
  xb2[(size_t)m*16 + 8 + wdx] = q;
}

// ---------------- conv3: binary 1x1 256->256 ----------------
__global__ __launch_bounds__(256) void conv3_kernel(
    const uint32_t* __restrict__ xb2, const uint32_t* __restrict__ wb3,
    int16_t* __restrict__ out3) {
  int m = blockIdx.x*256 + threadIdx.x;   // NS2
  int n = m / S2, hw = m % S2;
  const uint32_t* xw = xb2 + (size_t)m*16;
  uint32_t P[8], Q[8];
  #pragma unroll
  for (int i = 0; i < 8; ++i) { P[i] = xw[i]; Q[i] = xw[8+i]; }
  int co0 = blockIdx.y * 32;
  size_t obase = ((size_t)n*COUT)*S2 + hw;
  #pragma unroll 2
  for (int co = co0; co < co0 + 32; ++co) {
    const uint32_t* w = wb3 + (size_t)co*16;
    int acc = 0;
    #pragma unroll
    for (int i = 0; i < 8; ++i) {
      uint32_t wp = w[i], wn = w[8+i];
      acc += __popc(P[i]&wp) + __popc(Q[i]&wn) - __popc(P[i]&wn) - __popc(Q[i]&wp);
    }
    out3[obase + (size_t)co*S2] = (int16_t)acc;
  }
}

// ---------------- fused residual (bf16 MFMA GEMM) + BN3(prelu(out3)) + add ----------------
// block 256 = 4 waves; wave: 16m x 64co; grid (NS2/64, COUT/64).
// A frag: lane holds x[m0+(lane&15)][ks*32+(lane>>4)*8+j]; B: w[co][same k]; C/D row=(lane>>4)*4+r.
__global__ __launch_bounds__(256) void resfinal_kernel(
    const uint16_t* __restrict__ xg, const uint16_t* __restrict__ wb,
    const int16_t* __restrict__ out3,
    const float* __restrict__ a3, const float* __restrict__ g3,
    const float* __restrict__ b3, const int* __restrict__ acc3,
    float* __restrict__ out) {
  int lane = threadIdx.x & 63;
  int wid  = threadIdx.x >> 6;
  int m0  = blockIdx.x*64 + wid*16;
  int co0 = blockIdx.y*64;
  int r16 = lane & 15, hi = lane >> 4;
  int koff = hi * 8;

  const bf16x8* arow = (const bf16x8*)(xg + (size_t)(m0 + r16)*CIN + koff);
  bf16x8 af0 = arow[0], af1 = arow[4], af2 = arow[8], af3 = arow[12];

  f32x4 d0, d1, d2, d3;
  {
    const bf16x8* brow = (const bf16x8*)(wb + (size_t)(co0 + r16)*CIN + koff);
    f32x4 a = {0.f,0.f,0.f,0.f};
    a = __builtin_amdgcn_mfma_f32_16x16x32_bf16(af0, brow[0],  a, 0,0,0);
    a = __builtin_amdgcn_mfma_f32_16x16x32_bf16(af1, brow[4],  a, 0,0,0);
    a = __builtin_amdgcn_mfma_f32_16x16x32_bf16(af2, brow[8],  a, 0,0,0);
    a = __builtin_amdgcn_mfma_f32_16x16x32_bf16(af3, brow[12], a, 0,0,0);
    d0 = a;
  }
  {
    const bf16x8* brow = (const bf16x8*)(wb + (size_t)(co0 + 16 + r16)*CIN + koff);
    f32x4 a = {0.f,0.f,0.f,0.f};
    a = __builtin_amdgcn_mfma_f32_16x16x32_bf16(af0, brow[0],  a, 0,0,0);
    a = __builtin_amdgcn_mfma_f32_16x16x32_bf16(af1, brow[4],  a, 0,0,0);
    a = __builtin_amdgcn_mfma_f32_16x16x32_bf16(af2, brow[8],  a, 0,0,0);
    a = __builtin_amdgcn_mfma_f32_16x16x32_bf16(af3, brow[12], a, 0,0,0);
    d1 = a;
  }
  {
    const bf16x8* brow = (const bf16x8*)(wb + (size_t)(co0 + 32 + r16)*CIN + koff);
    f32x4 a = {0.f,0.f,0.f,0.f};
    a = __builtin_amdgcn_mfma_f32_16x16x32_bf16(af0, brow[0],  a, 0,0,0);
    a = __builtin_amdgcn_mfma_f32_16x16x32_bf16(af1, brow[4],  a, 0,0,0);
    a = __builtin_amdgcn_mfma_f32_16x16x32_bf16(af2, brow[8],  a, 0,0,0);
    a = __builtin_amdgcn_mfma_f32_16x16x32_bf16(af3, brow[12], a, 0,0,0);
    d2 = a;
  }
  {
    const bf16x8* brow = (const bf16x8*)(wb + (size_t)(co0 + 48 + r16)*CIN + koff);
    f32x4 a = {0.f,0.f,0.f,0.f};
    a = __builtin_amdgcn_mfma_f32_16x16x32_bf16(af0, brow[0],  a, 0,0,0);
    a = __builtin_amdgcn_mfma_f32_16x16x32_bf16(af1, brow[4],  a, 0,0,0);
    a = __builtin_amdgcn_mfma_f32_16x16x32_bf16(af2, brow[8],  a, 0,0,0);
    a = __builtin_amdgcn_mfma_f32_16x16x32_bf16(af3, brow[12], a, 0,0,0);
    d3 = a;
  }

  // epilogue: lane writes rows m0 + hi*4 + r, col co0 + t*16 + r16
  int mrow = m0 + hi*4;
  int n  = mrow / S2;               // 16-m tiles never straddle n (784 % 16 == 0)
  int hw = mrow - n*S2;
  f32x4 dd[4] = {d0, d1, d2, d3};
  #pragma unroll
  for (int t = 0; t < 4; ++t) {
    int co = co0 + t*16 + r16;
    float av = a3[co], sc, sh;
    bn_finalize(acc3 + co*4, av, g3[co], b3[co], 1.f/NS2, sc, sh);
    size_t o = ((size_t)n*COUT + co)*S2 + hw;
    #pragma unroll
    for (int r = 0; r < 4; ++r) {
      float f = (float)out3[o + r];
      float pp = f > 0.f ? f : av*f;
      out[o + r] = pp*sc + sh + dd[t][r];
    }
  }
}

extern "C" void kernel_launch(void* const* d_in, const int* in_sizes, int n_in,
                              void* d_out, int out_size, void* d_ws, size_t ws_size,
                              hipStream_t stream) {
  (void)in_sizes; (void)n_in; (void)out_size; (void)ws_size;
  const float* x    = (const float*)d_in[0];
  const float* w1   = (const float*)d_in[1];
  const float* a1   = (const float*)d_in[2];
  const float* g1   = (const float*)d_in[3];
  const float* b1   = (const float*)d_in[4];
  const float* wdw  = (const float*)d_in[5];
  const float* a2   = (const float*)d_in[6];
  const float* g2   = (const float*)d_in[7];
  const float* b2   = (const float*)d_in[8];
  const float* w3   = (const float*)d_in[9];
  const float* a3   = (const float*)d_in[10];
  const float* g3   = (const float*)d_in[11];
  const float* b3   = (const float*)d_in[12];
  const float* wadj = (const float*)d_in[13];
  float* out = (float*)d_out;

  char* ws = (char*)d_ws;
  uint32_t* xbits = (uint32_t*)(ws + OFF_XBITS);
  uint32_t* wb1   = (uint32_t*)(ws + OFF_WB1);
  uint32_t* wb3   = (uint32_t*)(ws + OFF_WB3);
  int8_t*   wdws  = (int8_t*)  (ws + OFF_WDW);
  int*      acc1  = (int*)     (ws + OFF_ACC);
  int*      acc2  = acc1 + 256*4;
  int*      acc3  = acc2 + 256*4;
  int*      thr   = (int*)     (ws + OFF_THR);   // [4][256]: Tp1,Tn1,Tp2,Tn2
  int*      Tp1 = thr, *Tn1 = thr + 256, *Tp2 = thr + 512, *Tn2 = thr + 768;
  uint32_t* wbadj = (uint32_t*)(ws + OFF_WBADJ);
  uint32_t* xg    = (uint32_t*)(ws + OFF_XG);
  int8_t*   out1  = (int8_t*)  (ws + OFF_OUT1);
  int8_t*   out2  = (int8_t*)  (ws + OFF_OUT2);
  uint32_t* xb2   = (uint32_t*)(ws + OFF_XB2);
  int16_t*  out3  = (int16_t*) (ws + OFF_OUT3);

  hipMemsetAsync(acc1, 0, 3*256*4*sizeof(int), stream);
  packw_kernel<<<256, 64, 0, stream>>>(w1, w3, wdw, wadj, wb1, wb3, wdws, wbadj);
  packx_kernel<<<dim3(NS1/256, 4), 256, 0, stream>>>(x, xbits, xg);
  conv1_kernel<<<dim3(NS1/256, 8), 256, 0, stream>>>(xbits, wb1, out1);
  stats_i8_kernel<<<dim3(256, 8), 256, 0, stream>>>(out1, acc1, S1, 3136);
  thr_kernel<<<1, 256, 0, stream>>>(acc1, a1, g1, b1, 1.f/NS1, -128, 127, Tp1, Tn1);
  dw_kernel<<<NB*COUT*HO/256, 256, 0, stream>>>(out1, wdws, Tp1, Tn1, out2);
  stats_i8_kernel<<<dim3(256, 4), 256, 0, stream>>>(out2, acc2, S2, 1568);
  thr_kernel<<<1, 256, 0, stream>>>(acc2, a2, g2, b2, 1.f/NS2, -9, 9, Tp2, Tn2);
  pack2_kernel<<<dim3(NS2/256, 8), 256, 0, stream>>>(out2, Tp2, Tn2, xb2);
  conv3_kernel<<<dim3(NS2/256, 8), 256, 0, stream>>>(xb2, wb3, out3);
  stats_i16_kernel<<<dim3(256, 4), 256, 0, stream>>>(out3, acc3, S2, 3136);
  resfinal_kernel<<<dim3(NS2/64, COUT/64), 256, 0, stream>>>(
      (const uint16_t*)xg, (const uint16_t*)wbadj, out3, a3, g3, b3, acc3, out);
}

// Round 8
// 156.993 us; speedup vs baseline: 1.4658x; 1.1483x over previous
//
#include <hip/hip_runtime.h>
#include <stdint.h>

// ---- problem dims ----
#define NB   32
#define CIN  128
#define COUT 256
#define HH   56
#define WW   56
#define S1   (HH*WW)      // 3136
#define HO   28
#define WO   28
#define S2   (HO*WO)      // 784
#define NS1  (NB*S1)      // 100352
#define NS2  (NB*S2)      // 25088
#define TOT2 (NS2*COUT)   // 6422528
#define EPSV 1e-5f

// ---- workspace layout (bytes) ----
constexpr size_t OFF_XBITS = 0;                                 // NS1*8*4 = 3,211,264
constexpr size_t OFF_WB1   = OFF_XBITS + (size_t)NS1*8*4;       // 8 KB
constexpr size_t OFF_WB3   = OFF_WB1 + 256*8*4;                 // 16 KB
constexpr size_t OFF_WDW   = OFF_WB3 + 256*16*4;                // 4 KB
constexpr size_t OFF_ACC   = OFF_WDW + 4096;                    // 12 KB
constexpr size_t OFF_THR   = OFF_ACC + 3*256*4*sizeof(int);     // 4 KB
constexpr size_t OFF_WBADJ = OFF_THR + 4*256*sizeof(int);       // 256*128*2 = 65,536
constexpr size_t OFF_XG    = OFF_WBADJ + (size_t)COUT*CIN*2;    // NS2*128*2 = 6,422,528
constexpr size_t OFF_OUT1  = OFF_XG + (size_t)NS2*CIN*2;        // NS1*COUT i8 = 25,690,112
constexpr size_t OFF_OUT2  = OFF_OUT1 + (size_t)NS1*COUT;       // i8 6,422,528
constexpr size_t OFF_XB2   = OFF_OUT2 + (size_t)TOT2;           // NS2*16*4 = 1,605,632
constexpr size_t OFF_OUT3  = OFF_XB2 + (size_t)NS2*16*4;        // i16 12,845,056
// total ~56 MB

typedef __attribute__((ext_vector_type(8))) short bf16x8;
typedef __attribute__((ext_vector_type(4))) float f32x4;

__device__ __forceinline__ uint32_t f2bf(float v) {
  uint32_t u = __float_as_uint(v);
  return (u + 0x7fffu + ((u >> 16) & 1u)) >> 16;   // RNE bf16 bits
}

// finalize BN scale/shift from exact integer sums of prelu output
__device__ __forceinline__ void bn_finalize(const int* __restrict__ acc4,
                                            float a, float g, float b, float inv_ns,
                                            float& sc, float& sh) {
  float ps = (float)acc4[0];   // sum of v where v>0
  float ng = (float)acc4[1];   // sum of v where v<0
  float pq = (float)acc4[2];   // sum of v^2 where v>0
  float nq = (float)acc4[3];   // sum of v^2 where v<0
  float mean = (ps + a*ng) * inv_ns;
  float ex2  = (pq + a*a*nq) * inv_ns;
  float var  = ex2 - mean*mean;
  float rs   = rsqrtf(var + EPSV);
  sc = rs * g;
  sh = b - mean * sc;
}

// ---------------- pack weights + zero the stats accumulators ----------------
__global__ __launch_bounds__(64) void packw_kernel(
    const float* __restrict__ w1, const float* __restrict__ w3,
    const float* __restrict__ wdw, const float* __restrict__ wadj,
    uint32_t* __restrict__ wb1, uint32_t* __restrict__ wb3,
    int8_t* __restrict__ wdws, uint32_t* __restrict__ wbadj,
    int* __restrict__ accbase) {
  int co = blockIdx.x;
  int l  = threadIdx.x;
  // zero acc1/acc2/acc3 for this channel (replaces hipMemsetAsync graph node)
  if (l < 12) {
    int set = l >> 2, k = l & 3;
    accbase[set*1024 + co*4 + k] = 0;
  }
  for (int h = 0; h < 2; ++h) {
    float v = w1[(size_t)co*CIN + h*64 + l];
    unsigned long long bp = __ballot(v > 0.f);
    unsigned long long bn = __ballot(v < 0.f);
    if (l == 0) {
      wb1[co*8 + 2*h    ] = (uint32_t)bp;
      wb1[co*8 + 2*h + 1] = (uint32_t)(bp >> 32);
      wb1[co*8 + 4 + 2*h    ] = (uint32_t)bn;
      wb1[co*8 + 4 + 2*h + 1] = (uint32_t)(bn >> 32);
    }
  }
  for (int h = 0; h < 4; ++h) {
    float v = w3[(size_t)co*COUT + h*64 + l];
    unsigned long long bp = __ballot(v > 0.f);
    unsigned long long bn = __ballot(v < 0.f);
    if (l == 0) {
      wb3[co*16 + 2*h    ] = (uint32_t)bp;
      wb3[co*16 + 2*h + 1] = (uint32_t)(bp >> 32);
      wb3[co*16 + 8 + 2*h    ] = (uint32_t)bn;
      wb3[co*16 + 8 + 2*h + 1] = (uint32_t)(bn >> 32);
    }
  }
  if (l < 9) {
    float v = wdw[co*9 + l];
    wdws[co*9 + l] = (int8_t)((v > 0.f) - (v < 0.f));
  }
  // bf16 w_adj, layout [co][c], packed 2 per dword
  {
    float v0 = wadj[(size_t)co*CIN + 2*l];
    float v1 = wadj[(size_t)co*CIN + 2*l + 1];
    wbadj[co*64 + l] = f2bf(v0) | (f2bf(v1) << 16);
  }
}

// ---------------- pack x into bitplanes + bf16 compact stride-2 tile ----------------
__global__ __launch_bounds__(256) void packx_kernel(
    const float* __restrict__ x, uint32_t* __restrict__ xbits,
    uint32_t* __restrict__ xg) {
  int m = blockIdx.x*256 + threadIdx.x;     // m = n*S1 + hw
  int wdx = blockIdx.y;                     // 0..3
  int n = m / S1, hw = m % S1;
  size_t base = ((size_t)n*CIN + wdx*32)*S1 + hw;
  uint32_t p = 0, q = 0;
  uint32_t bv[16];
  #pragma unroll
  for (int j = 0; j < 32; ++j) {
    float v = x[base + (size_t)j*S1];
    p |= (uint32_t)(v > 0.f) << j;
    q |= (uint32_t)(v < 0.f) << j;
    uint32_t b = f2bf(v);
    if (j & 1) bv[j >> 1] |= b << 16; else bv[j >> 1] = b;
  }
  xbits[(size_t)m*8 + wdx    ] = p;
  xbits[(size_t)m*8 + 4 + wdx] = q;
  int h = hw / WW, w = hw % WW;
  if (((h | w) & 1) == 0) {
    int m2 = n*S2 + (h >> 1)*WO + (w >> 1);
    uint4* dst = (uint4*)(xg + (size_t)m2*64 + wdx*16);
    dst[0] = make_uint4(bv[0],  bv[1],  bv[2],  bv[3]);
    dst[1] = make_uint4(bv[4],  bv[5],  bv[6],  bv[7]);
    dst[2] = make_uint4(bv[8],  bv[9],  bv[10], bv[11]);
    dst[3] = make_uint4(bv[12], bv[13], bv[14], bv[15]);
  }
}

// ---------------- conv1: binary 1x1 via XOR popcount (fast path) ----------------
// sign(x) in {-1,0,1}: when the pixel has no zero channels (overwhelmingly common),
// dot = 128 - 2*popc(p^a). Rare zero-containing pixels take the exact 2-plane path.
__global__ __launch_bounds__(256) void conv1_kernel(
    const uint32_t* __restrict__ xb, const uint32_t* __restrict__ wb,
    int8_t* __restrict__ out1) {
  int m = blockIdx.x*256 + threadIdx.x;
  int n = m / S1, hw = m % S1;
  const uint32_t* xw = xb + (size_t)m*8;
  uint32_t p0 = xw[0], p1 = xw[1], p2 = xw[2], p3 = xw[3];
  uint32_t q0 = xw[4], q1 = xw[5], q2 = xw[6], q3 = xw[7];
  int co0 = blockIdx.y * 32;
  size_t obase = ((size_t)n*COUT)*S1 + hw;
  bool nozero = (((p0|q0) & (p1|q1) & (p2|q2) & (p3|q3)) == 0xffffffffu);
  if (nozero) {
    #pragma unroll 4
    for (int co = co0; co < co0 + 32; ++co) {
      const uint32_t* w8 = wb + (size_t)co*8;
      int s = __popc(p0 ^ w8[0]) + __popc(p1 ^ w8[1])
            + __popc(p2 ^ w8[2]) + __popc(p3 ^ w8[3]);
      int acc = 128 - 2*s;
      if (acc > 127) acc = 127;
      out1[obase + (size_t)co*S1] = (int8_t)acc;
    }
  } else {
    #pragma unroll 4
    for (int co = co0; co < co0 + 32; ++co) {
      const uint32_t* w8 = wb + (size_t)co*8;
      uint32_t a0 = w8[0], a1 = w8[1], a2 = w8[2], a3 = w8[3];
      uint32_t b0 = w8[4], b1 = w8[5], b2 = w8[6], b3 = w8[7];
      int acc = __popc(p0&a0) + __popc(p1&a1) + __popc(p2&a2) + __popc(p3&a3)
              + __popc(q0&b0) + __popc(q1&b1) + __popc(q2&b2) + __popc(q3&b3)
              - __popc(p0&b0) - __popc(p1&b1) - __popc(p2&b2) - __popc(p3&b3)
              - __popc(q0&a0) - __popc(q1&a1) - __popc(q2&a2) - __popc(q3&a3);
      if (acc > 127) acc = 127;
      out1[obase + (size_t)co*S1] = (int8_t)acc;
    }
  }
}

// ---------------- per-channel integer stats (int8 buffer) ----------------
__global__ __launch_bounds__(256) void stats_i8_kernel(
    const int8_t* __restrict__ buf, int* __restrict__ accum,
    int s_sp, int quads_per_block) {
  int co = blockIdx.x, slice = blockIdx.y;
  int q0 = slice * quads_per_block;
  int psum = 0, nsum = 0, psq = 0, nsq = 0;
  for (int i = threadIdx.x; i < quads_per_block; i += 256) {
    int flat = (q0 + i) * 4;
    int n = flat / s_sp, hw = flat % s_sp;
    char4 v = *reinterpret_cast<const char4*>(buf + (size_t)(n*COUT + co)*s_sp + hw);
    int vs[4] = {v.x, v.y, v.z, v.w};
    #pragma unroll
    for (int k = 0; k < 4; ++k) {
      int f = vs[k];
      if (f > 0) { psum += f; psq += f*f; } else { nsum += f; nsq += f*f; }
    }
  }
  __shared__ int r0[256], r1[256], r2[256], r3[256];
  int t = threadIdx.x;
  r0[t] = psum; r1[t] = nsum; r2[t] = psq; r3[t] = nsq;
  __syncthreads();
  for (int s = 128; s > 0; s >>= 1) {
    if (t < s) { r0[t]+=r0[t+s]; r1[t]+=r1[t+s]; r2[t]+=r2[t+s]; r3[t]+=r3[t+s]; }
    __syncthreads();
  }
  if (t == 0) {
    atomicAdd(&accum[co*4+0], r0[0]);
    atomicAdd(&accum[co*4+1], r1[0]);
    atomicAdd(&accum[co*4+2], r2[0]);
    atomicAdd(&accum[co*4+3], r3[0]);
  }
}

__global__ __launch_bounds__(256) void stats_i16_kernel(
    const int16_t* __restrict__ buf, int* __restrict__ accum,
    int s_sp, int pairs_per_block) {
  int co = blockIdx.x, slice = blockIdx.y;
  int p0i = slice * pairs_per_block;
  int psum = 0, nsum = 0, psq = 0, nsq = 0;
  for (int i = threadIdx.x; i < pairs_per_block; i += 256) {
    int flat = (p0i + i) * 2;
    int n = flat / s_sp, hw = flat % s_sp;
    short2 v = *reinterpret_cast<const short2*>(buf + (size_t)(n*COUT + co)*s_sp + hw);
    int vs[2] = {v.x, v.y};
    #pragma unroll
    for (int k = 0; k < 2; ++k) {
      int f = vs[k];
      if (f > 0) { psum += f; psq += f*f; } else { nsum += f; nsq += f*f; }
    }
  }
  __shared__ int r0[256], r1[256], r2[256], r3[256];
  int t = threadIdx.x;
  r0[t] = psum; r1[t] = nsum; r2[t] = psq; r3[t] = nsq;
  __syncthreads();
  for (int s = 128; s > 0; s >>= 1) {
    if (t < s) { r0[t]+=r0[t+s]; r1[t]+=r1[t+s]; r2[t]+=r2[t+s]; r3[t]+=r3[t+s]; }
    __syncthreads();
  }
  if (t == 0) {
    atomicAdd(&accum[co*4+0], r0[0]);
    atomicAdd(&accum[co*4+1], r1[0]);
    atomicAdd(&accum[co*4+2], r2[0]);
    atomicAdd(&accum[co*4+3], r3[0]);
  }
}

// ---------------- thresholds: sign(BN(prelu(v))) == (v>=Tpos) - (v<=Tneg) ----------------
__global__ __launch_bounds__(256) void thr_kernel(
    const int* __restrict__ accum, const float* __restrict__ a,
    const float* __restrict__ g, const float* __restrict__ b,
    float inv_ns, int vlo, int vhi,
    int* __restrict__ Tpos, int* __restrict__ Tneg) {
  int co = threadIdx.x;
  float av = a[co], sc, sh;
  bn_finalize(accum + co*4, av, g[co], b[co], inv_ns, sc, sh);
  int tp = vhi + 1, tn = vlo - 1;
  for (int v = vlo; v <= vhi; ++v) {
    float f = (float)v;
    float p = f > 0.f ? f : av*f;
    float tv = p*sc + sh;
    if (tv > 0.f && v < tp) tp = v;    // min v with tv>0
    if (tv < 0.f && v > tn) tn = v;    // max v with tv<0
  }
  Tpos[co] = tp;
  Tneg[co] = tn;
}

// ---------------- depthwise 3x3 s2 p1 via thresholds, register sliding window ----------------
__device__ __forceinline__ int thr_sgn(uint32_t d, int k, int Tp, int Tn) {
  int v = (int)(int8_t)(d >> (8*k));
  return (v >= Tp) - (v <= Tn);
}

__global__ __launch_bounds__(256) void dw_kernel(
    const int8_t* __restrict__ out1, const int8_t* __restrict__ wdws,
    const int* __restrict__ Tp1, const int* __restrict__ Tn1,
    int8_t* __restrict__ out2) {
  int idx = blockIdx.x*256 + threadIdx.x;   // over NB*COUT*HO = 229376
  int ho = idx % HO;
  int nc = idx / HO;                        // n*COUT + co
  int co = nc & (COUT-1);
  int Tp = Tp1[co], Tn = Tn1[co];

  int wv[9];
  #pragma unroll
  for (int k = 0; k < 9; ++k) wv[k] = wdws[co*9 + k];

  const int8_t* base = out1 + (size_t)nc * S1;
  const uint32_t* row0 = (const uint32_t*)(base + (2*ho - 1)*WW);
  const uint32_t* row1 = (const uint32_t*)(base + (2*ho    )*WW);
  const uint32_t* row2 = (const uint32_t*)(base + (2*ho + 1)*WW);
  bool v0 = (ho > 0);
  int m0 = v0 ? -1 : 0;    // sign mask for top pad row (pad applied AFTER sign -> 0)

  uint32_t* o32 = (uint32_t*)(out2 + (size_t)nc*S2 + ho*WO);

  int c0 = 0, c1 = 0, c2 = 0;   // carry: sign at col 4q-1 (left pad -> 0)
  uint32_t obuf = 0;
  #pragma unroll
  for (int q = 0; q < 14; ++q) {
    uint32_t d0 = v0 ? row0[q] : 0u;
    uint32_t d1 = row1[q];
    uint32_t d2 = row2[q];
    int s00 = thr_sgn(d0,0,Tp,Tn) & m0, s01 = thr_sgn(d0,1,Tp,Tn) & m0,
        s02 = thr_sgn(d0,2,Tp,Tn) & m0, s03 = thr_sgn(d0,3,Tp,Tn) & m0;
    int s10 = thr_sgn(d1,0,Tp,Tn), s11 = thr_sgn(d1,1,Tp,Tn),
        s12 = thr_sgn(d1,2,Tp,Tn), s13 = thr_sgn(d1,3,Tp,Tn);
    int s20 = thr_sgn(d2,0,Tp,Tn), s21 = thr_sgn(d2,1,Tp,Tn),
        s22 = thr_sgn(d2,2,Tp,Tn), s23 = thr_sgn(d2,3,Tp,Tn);
    int a0 = c0*wv[0] + s00*wv[1] + s01*wv[2]
           + c1*wv[3] + s10*wv[4] + s11*wv[5]
           + c2*wv[6] + s20*wv[7] + s21*wv[8];
    int a1 = s01*wv[0] + s02*wv[1] + s03*wv[2]
           + s11*wv[3] + s12*wv[4] + s13*wv[5]
           + s21*wv[6] + s22*wv[7] + s23*wv[8];
    c0 = s03; c1 = s13; c2 = s23;
    if ((q & 1) == 0) {
      obuf = (uint32_t)(a0 & 0xff) | ((uint32_t)(a1 & 0xff) << 8);
    } else {
      obuf |= ((uint32_t)(a0 & 0xff) << 16) | ((uint32_t)(a1 & 0xff) << 24);
      o32[q >> 1] = obuf;
    }
  }
}

// ---------------- pack sign(BN2(prelu(out2))) via thresholds, split over wdx ----------------
__global__ __launch_bounds__(256) void pack2_kernel(
    const int8_t* __restrict__ out2,
    const int* __restrict__ Tp2, const int* __restrict__ Tn2,
    uint32_t* __restrict__ xb2) {
  int m = blockIdx.x*256 + threadIdx.x;   // n*S2 + hw
  int wdx = blockIdx.y;                   // 0..7
  int n = m / S2, hw = m % S2;
  uint32_t p = 0, q = 0;
  #pragma unroll
  for (int j = 0; j < 32; ++j) {
    int c = wdx*32 + j;
    int v = out2[(size_t)(n*COUT + c)*S2 + hw];
    p |= (uint32_t)(v >= Tp2[c]) << j;
    q |= (uint32_t)(v <= Tn2[c]) << j;
  }
  xb2[(size_t)m*16 + wdx    ] = p;
  xb2[(size_t)m*16 + 8 + wdx] = q;
}

// ---------------- conv3: binary 1x1 256->256 ----------------
__global__ __launch_bounds__(256) void conv3_kernel(
    const uint32_t* __restrict__ xb2, const uint32_t* __restrict__ wb3,
    int16_t* __restrict__ out3) {
  int m = blockIdx.x*256 + threadIdx.x;   // NS2
  int n = m / S2, hw = m % S2;
  const uint32_t* xw = xb2 + (size_t)m*16;
  uint32_t P[8], Q[8];
  #pragma unroll
  for (int i = 0; i < 8; ++i) { P[i] = xw[i]; Q[i] = xw[8+i]; }
  int co0 = blockIdx.y * 32;
  size_t obase = ((size_t)n*COUT)*S2 + hw;
  #pragma unroll 2
  for (int co = co0; co < co0 + 32; ++co) {
    const uint32_t* w = wb3 + (size_t)co*16;
    int acc = 0;
    #pragma unroll
    for (int i = 0; i < 8; ++i) {
      uint32_t wp = w[i], wn = w[8+i];
      acc += __popc(P[i]&wp) + __popc(Q[i]&wn) - __popc(P[i]&wn) - __popc(Q[i]&wp);
    }
    out3[obase + (size_t)co*S2] = (int16_t)acc;
  }
}

// ---------------- fused residual (bf16 MFMA GEMM) + BN3(prelu(out3)) + add ----------------
__global__ __launch_bounds__(256) void resfinal_kernel(
    const uint16_t* __restrict__ xg, const uint16_t* __restrict__ wb,
    const int16_t* __restrict__ out3,
    const float* __restrict__ a3, const float* __restrict__ g3,
    const float* __restrict__ b3, const int* __restrict__ acc3,
    float* __restrict__ out) {
  int lane = threadIdx.x & 63;
  int wid  = threadIdx.x >> 6;
  int m0  = blockIdx.x*64 + wid*16;
  int co0 = blockIdx.y*64;
  int r16 = lane & 15, hi = lane >> 4;
  int koff = hi * 8;

  const bf16x8* arow = (const bf16x8*)(xg + (size_t)(m0 + r16)*CIN + koff);
  bf16x8 af0 = arow[0], af1 = arow[4], af2 = arow[8], af3 = arow[12];

  f32x4 d0, d1, d2, d3;
  {
    const bf16x8* brow = (const bf16x8*)(wb + (size_t)(co0 + r16)*CIN + koff);
    f32x4 a = {0.f,0.f,0.f,0.f};
    a = __builtin_amdgcn_mfma_f32_16x16x32_bf16(af0, brow[0],  a, 0,0,0);
    a = __builtin_amdgcn_mfma_f32_16x16x32_bf16(af1, brow[4],  a, 0,0,0);
    a = __builtin_amdgcn_mfma_f32_16x16x32_bf16(af2, brow[8],  a, 0,0,0);
    a = __builtin_amdgcn_mfma_f32_16x16x32_bf16(af3, brow[12], a, 0,0,0);
    d0 = a;
  }
  {
    const bf16x8* brow = (const bf16x8*)(wb + (size_t)(co0 + 16 + r16)*CIN + koff);
    f32x4 a = {0.f,0.f,0.f,0.f};
    a = __builtin_amdgcn_mfma_f32_16x16x32_bf16(af0, brow[0],  a, 0,0,0);
    a = __builtin_amdgcn_mfma_f32_16x16x32_bf16(af1, brow[4],  a, 0,0,0);
    a = __builtin_amdgcn_mfma_f32_16x16x32_bf16(af2, brow[8],  a, 0,0,0);
    a = __builtin_amdgcn_mfma_f32_16x16x32_bf16(af3, brow[12], a, 0,0,0);
    d1 = a;
  }
  {
    const bf16x8* brow = (const bf16x8*)(wb + (size_t)(co0 + 32 + r16)*CIN + koff);
    f32x4 a = {0.f,0.f,0.f,0.f};
    a = __builtin_amdgcn_mfma_f32_16x16x32_bf16(af0, brow[0],  a, 0,0,0);
    a = __builtin_amdgcn_mfma_f32_16x16x32_bf16(af1, brow[4],  a, 0,0,0);
    a = __builtin_amdgcn_mfma_f32_16x16x32_bf16(af2, brow[8],  a, 0,0,0);
    a = __builtin_amdgcn_mfma_f32_16x16x32_bf16(af3, brow[12], a, 0,0,0);
    d2 = a;
  }
  {
    const bf16x8* brow = (const bf16x8*)(wb + (size_t)(co0 + 48 + r16)*CIN + koff);
    f32x4 a = {0.f,0.f,0.f,0.f};
    a = __builtin_amdgcn_mfma_f32_16x16x32_bf16(af0, brow[0],  a, 0,0,0);
    a = __builtin_amdgcn_mfma_f32_16x16x32_bf16(af1, brow[4],  a, 0,0,0);
    a = __builtin_amdgcn_mfma_f32_16x16x32_bf16(af2, brow[8],  a, 0,0,0);
    a = __builtin_amdgcn_mfma_f32_16x16x32_bf16(af3, brow[12], a, 0,0,0);
    d3 = a;
  }

  int mrow = m0 + hi*4;
  int n  = mrow / S2;               // 16-m tiles never straddle n (784 % 16 == 0)
  int hw = mrow - n*S2;
  f32x4 dd[4] = {d0, d1, d2, d3};
  #pragma unroll
  for (int t = 0; t < 4; ++t) {
    int co = co0 + t*16 + r16;
    float av = a3[co], sc, sh;
    bn_finalize(acc3 + co*4, av, g3[co], b3[co], 1.f/NS2, sc, sh);
    size_t o = ((size_t)n*COUT + co)*S2 + hw;
    #pragma unroll
    for (int r = 0; r < 4; ++r) {
      float f = (float)out3[o + r];
      float pp = f > 0.f ? f : av*f;
      out[o + r] = pp*sc + sh + dd[t][r];
    }
  }
}

extern "C" void kernel_launch(void* const* d_in, const int* in_sizes, int n_in,
                              void* d_out, int out_size, void* d_ws, size_t ws_size,
                              hipStream_t stream) {
  (void)in_sizes; (void)n_in; (void)out_size; (void)ws_size;
  const float* x    = (const float*)d_in[0];
  const float* w1   = (const float*)d_in[1];
  const float* a1   = (const float*)d_in[2];
  const float* g1   = (const float*)d_in[3];
  const float* b1   = (const float*)d_in[4];
  const float* wdw  = (const float*)d_in[5];
  const float* a2   = (const float*)d_in[6];
  const float* g2   = (const float*)d_in[7];
  const float* b2   = (const float*)d_in[8];
  const float* w3   = (const float*)d_in[9];
  const float* a3   = (const float*)d_in[10];
  const float* g3   = (const float*)d_in[11];
  const float* b3   = (const float*)d_in[12];
  const float* wadj = (const float*)d_in[13];
  float* out = (float*)d_out;

  char* ws = (char*)d_ws;
  uint32_t* xbits = (uint32_t*)(ws + OFF_XBITS);
  uint32_t* wb1   = (uint32_t*)(ws + OFF_WB1);
  uint32_t* wb3   = (uint32_t*)(ws + OFF_WB3);
  int8_t*   wdws  = (int8_t*)  (ws + OFF_WDW);
  int*      acc1  = (int*)     (ws + OFF_ACC);
  int*      acc2  = acc1 + 256*4;
  int*      acc3  = acc2 + 256*4;
  int*      thr   = (int*)     (ws + OFF_THR);   // [4][256]: Tp1,Tn1,Tp2,Tn2
  int*      Tp1 = thr, *Tn1 = thr + 256, *Tp2 = thr + 512, *Tn2 = thr + 768;
  uint32_t* wbadj = (uint32_t*)(ws + OFF_WBADJ);
  uint32_t* xg    = (uint32_t*)(ws + OFF_XG);
  int8_t*   out1  = (int8_t*)  (ws + OFF_OUT1);
  int8_t*   out2  = (int8_t*)  (ws + OFF_OUT2);
  uint32_t* xb2   = (uint32_t*)(ws + OFF_XB2);
  int16_t*  out3  = (int16_t*) (ws + OFF_OUT3);

  packw_kernel<<<256, 64, 0, stream>>>(w1, w3, wdw, wadj, wb1, wb3, wdws, wbadj, acc1);
  packx_kernel<<<dim3(NS1/256, 4), 256, 0, stream>>>(x, xbits, xg);
  conv1_kernel<<<dim3(NS1/256, 8), 256, 0, stream>>>(xbits, wb1, out1);
  stats_i8_kernel<<<dim3(256, 8), 256, 0, stream>>>(out1, acc1, S1, 3136);
  thr_kernel<<<1, 256, 0, stream>>>(acc1, a1, g1, b1, 1.f/NS1, -128, 127, Tp1, Tn1);
  dw_kernel<<<NB*COUT*HO/256, 256, 0, stream>>>(out1, wdws, Tp1, Tn1, out2);
  stats_i8_kernel<<<dim3(256, 4), 256, 0, stream>>>(out2, acc2, S2, 1568);
  thr_kernel<<<1, 256, 0, stream>>>(acc2, a2, g2, b2, 1.f/NS2, -9, 9, Tp2, Tn2);
  pack2_kernel<<<dim3(NS2/256, 8), 256, 0, stream>>>(out2, Tp2, Tn2, xb2);
  conv3_kernel<<<dim3(NS2/256, 8), 256, 0, stream>>>(xb2, wb3, out3);
  stats_i16_kernel<<<dim3(256, 4), 256, 0, stream>>>(out3, acc3, S2, 3136);
  resfinal_kernel<<<dim3(NS2/64, COUT/64), 256, 0, stream>>>(
      (const uint16_t*)xg, (const uint16_t*)wbadj, out3, a3, g3, b3, acc3, out);
}

// Round 9
// 133.241 us; speedup vs baseline: 1.7271x; 1.1783x over previous
//
#include <hip/hip_runtime.h>
#include <stdint.h>

// ---- problem dims ----
#define NB   32
#define CIN  128
#define COUT 256
#define HH   56
#define WW   56
#define S1   (HH*WW)      // 3136
#define HO   28
#define WO   28
#define S2   (HO*WO)      // 784
#define NS1  (NB*S1)      // 100352
#define NS2  (NB*S2)      // 25088
#define TOT2 (NS2*COUT)   // 6422528
#define EPSV 1e-5f

// ---- workspace layout (bytes) ----
constexpr size_t OFF_XBITS = 0;                                 // NS1*8*4 = 3,211,264
constexpr size_t OFF_WB1   = OFF_XBITS + (size_t)NS1*8*4;       // 8 KB
constexpr size_t OFF_WB3   = OFF_WB1 + 256*8*4;                 // 16 KB
constexpr size_t OFF_WDW   = OFF_WB3 + 256*16*4;                // 4 KB
constexpr size_t OFF_ACC   = OFF_WDW + 4096;                    // 12 KB
constexpr size_t OFF_THR   = OFF_ACC + 3*256*4*sizeof(int);     // 4 KB
constexpr size_t OFF_WBADJ = OFF_THR + 4*256*sizeof(int);       // 256*128*2 = 65,536
constexpr size_t OFF_XG    = OFF_WBADJ + (size_t)COUT*CIN*2;    // NS2*128*2 = 6,422,528
constexpr size_t OFF_OUT1  = OFF_XG + (size_t)NS2*CIN*2;        // NS1*COUT i8 = 25,690,112
constexpr size_t OFF_OUT2  = OFF_OUT1 + (size_t)NS1*COUT;       // i8 6,422,528
constexpr size_t OFF_XB2   = OFF_OUT2 + (size_t)TOT2;           // NS2*16*4 = 1,605,632
constexpr size_t OFF_OUT3  = OFF_XB2 + (size_t)NS2*16*4;        // i16 12,845,056
// total ~56 MB

typedef __attribute__((ext_vector_type(8))) short bf16x8;
typedef __attribute__((ext_vector_type(4))) float f32x4;

__device__ __forceinline__ uint32_t f2bf(float v) {
  uint32_t u = __float_as_uint(v);
  return (u + 0x7fffu + ((u >> 16) & 1u)) >> 16;   // RNE bf16 bits
}

// finalize BN scale/shift from exact integer sums of prelu output
__device__ __forceinline__ void bn_finalize(const int* __restrict__ acc4,
                                            float a, float g, float b, float inv_ns,
                                            float& sc, float& sh) {
  float ps = (float)acc4[0];   // sum of v where v>0
  float ng = (float)acc4[1];   // sum of v where v<0
  float pq = (float)acc4[2];   // sum of v^2 where v>0
  float nq = (float)acc4[3];   // sum of v^2 where v<0
  float mean = (ps + a*ng) * inv_ns;
  float ex2  = (pq + a*a*nq) * inv_ns;
  float var  = ex2 - mean*mean;
  float rs   = rsqrtf(var + EPSV);
  sc = rs * g;
  sh = b - mean * sc;
}

// ---------------- pack x into bitplanes + bf16 stride-2 tile, fused weight pack ----------------
__global__ __launch_bounds__(256) void packx_kernel(
    const float* __restrict__ x, uint32_t* __restrict__ xbits,
    uint32_t* __restrict__ xg,
    const float* __restrict__ w1, const float* __restrict__ w3,
    const float* __restrict__ wdw, const float* __restrict__ wadj,
    uint32_t* __restrict__ wb1, uint32_t* __restrict__ wb3,
    int8_t* __restrict__ wdws, uint32_t* __restrict__ wbadj,
    int* __restrict__ accbase) {
  int wdx = blockIdx.y;                     // 0..3
  // fused weight pack + acc zero: wave 0 of blocks (bx<256, wdx==0)
  if (wdx == 0 && blockIdx.x < 256 && threadIdx.x < 64) {
    int co = blockIdx.x;
    int l  = threadIdx.x;
    if (l < 12) {
      int set = l >> 2, k = l & 3;
      accbase[set*1024 + co*4 + k] = 0;
    }
    for (int h = 0; h < 2; ++h) {
      float v = w1[(size_t)co*CIN + h*64 + l];
      unsigned long long bp = __ballot(v > 0.f);
      unsigned long long bn = __ballot(v < 0.f);
      if (l == 0) {
        wb1[co*8 + 2*h    ] = (uint32_t)bp;
        wb1[co*8 + 2*h + 1] = (uint32_t)(bp >> 32);
        wb1[co*8 + 4 + 2*h    ] = (uint32_t)bn;
        wb1[co*8 + 4 + 2*h + 1] = (uint32_t)(bn >> 32);
      }
    }
    for (int h = 0; h < 4; ++h) {
      float v = w3[(size_t)co*COUT + h*64 + l];
      unsigned long long bp = __ballot(v > 0.f);
      unsigned long long bn = __ballot(v < 0.f);
      if (l == 0) {
        wb3[co*16 + 2*h    ] = (uint32_t)bp;
        wb3[co*16 + 2*h + 1] = (uint32_t)(bp >> 32);
        wb3[co*16 + 8 + 2*h    ] = (uint32_t)bn;
        wb3[co*16 + 8 + 2*h + 1] = (uint32_t)(bn >> 32);
      }
    }
    if (l < 9) {
      float v = wdw[co*9 + l];
      wdws[co*9 + l] = (int8_t)((v > 0.f) - (v < 0.f));
    }
    {
      float v0 = wadj[(size_t)co*CIN + 2*l];
      float v1 = wadj[(size_t)co*CIN + 2*l + 1];
      wbadj[co*64 + l] = f2bf(v0) | (f2bf(v1) << 16);
    }
  }

  int m = blockIdx.x*256 + threadIdx.x;     // m = n*S1 + hw
  int n = m / S1, hw = m % S1;
  size_t base = ((size_t)n*CIN + wdx*32)*S1 + hw;
  uint32_t p = 0, q = 0;
  uint32_t bv[16];
  #pragma unroll
  for (int j = 0; j < 32; ++j) {
    float v = x[base + (size_t)j*S1];
    p |= (uint32_t)(v > 0.f) << j;
    q |= (uint32_t)(v < 0.f) << j;
    uint32_t b = f2bf(v);
    if (j & 1) bv[j >> 1] |= b << 16; else bv[j >> 1] = b;
  }
  xbits[(size_t)m*8 + wdx    ] = p;
  xbits[(size_t)m*8 + 4 + wdx] = q;
  int h = hw / WW, w = hw % WW;
  if (((h | w) & 1) == 0) {
    int m2 = n*S2 + (h >> 1)*WO + (w >> 1);
    uint4* dst = (uint4*)(xg + (size_t)m2*64 + wdx*16);
    dst[0] = make_uint4(bv[0],  bv[1],  bv[2],  bv[3]);
    dst[1] = make_uint4(bv[4],  bv[5],  bv[6],  bv[7]);
    dst[2] = make_uint4(bv[8],  bv[9],  bv[10], bv[11]);
    dst[3] = make_uint4(bv[12], bv[13], bv[14], bv[15]);
  }
}

// ---------------- conv1: binary 1x1 via XOR popcount (fast path) ----------------
__global__ __launch_bounds__(256) void conv1_kernel(
    const uint32_t* __restrict__ xb, const uint32_t* __restrict__ wb,
    int8_t* __restrict__ out1) {
  int m = blockIdx.x*256 + threadIdx.x;
  int n = m / S1, hw = m % S1;
  const uint32_t* xw = xb + (size_t)m*8;
  uint32_t p0 = xw[0], p1 = xw[1], p2 = xw[2], p3 = xw[3];
  uint32_t q0 = xw[4], q1 = xw[5], q2 = xw[6], q3 = xw[7];
  int co0 = blockIdx.y * 32;
  size_t obase = ((size_t)n*COUT)*S1 + hw;
  bool nozero = (((p0|q0) & (p1|q1) & (p2|q2) & (p3|q3)) == 0xffffffffu);
  if (nozero) {
    #pragma unroll 4
    for (int co = co0; co < co0 + 32; ++co) {
      const uint32_t* w8 = wb + (size_t)co*8;
      int s = __popc(p0 ^ w8[0]) + __popc(p1 ^ w8[1])
            + __popc(p2 ^ w8[2]) + __popc(p3 ^ w8[3]);
      int acc = 128 - 2*s;
      if (acc > 127) acc = 127;
      out1[obase + (size_t)co*S1] = (int8_t)acc;
    }
  } else {
    #pragma unroll 4
    for (int co = co0; co < co0 + 32; ++co) {
      const uint32_t* w8 = wb + (size_t)co*8;
      uint32_t a0 = w8[0], a1 = w8[1], a2 = w8[2], a3 = w8[3];
      uint32_t b0 = w8[4], b1 = w8[5], b2 = w8[6], b3 = w8[7];
      int acc = __popc(p0&a0) + __popc(p1&a1) + __popc(p2&a2) + __popc(p3&a3)
              + __popc(q0&b0) + __popc(q1&b1) + __popc(q2&b2) + __popc(q3&b3)
              - __popc(p0&b0) - __popc(p1&b1) - __popc(p2&b2) - __popc(p3&b3)
              - __popc(q0&a0) - __popc(q1&a1) - __popc(q2&a2) - __popc(q3&a3);
      if (acc > 127) acc = 127;
      out1[obase + (size_t)co*S1] = (int8_t)acc;
    }
  }
}

// ---------------- per-channel integer stats (int8 buffer) ----------------
__global__ __launch_bounds__(256) void stats_i8_kernel(
    const int8_t* __restrict__ buf, int* __restrict__ accum,
    int s_sp, int quads_per_block) {
  int co = blockIdx.x, slice = blockIdx.y;
  int q0 = slice * quads_per_block;
  int psum = 0, nsum = 0, psq = 0, nsq = 0;
  for (int i = threadIdx.x; i < quads_per_block; i += 256) {
    int flat = (q0 + i) * 4;
    int n = flat / s_sp, hw = flat % s_sp;
    char4 v = *reinterpret_cast<const char4*>(buf + (size_t)(n*COUT + co)*s_sp + hw);
    int vs[4] = {v.x, v.y, v.z, v.w};
    #pragma unroll
    for (int k = 0; k < 4; ++k) {
      int f = vs[k];
      if (f > 0) { psum += f; psq += f*f; } else { nsum += f; nsq += f*f; }
    }
  }
  __shared__ int r0[256], r1[256], r2[256], r3[256];
  int t = threadIdx.x;
  r0[t] = psum; r1[t] = nsum; r2[t] = psq; r3[t] = nsq;
  __syncthreads();
  for (int s = 128; s > 0; s >>= 1) {
    if (t < s) { r0[t]+=r0[t+s]; r1[t]+=r1[t+s]; r2[t]+=r2[t+s]; r3[t]+=r3[t+s]; }
    __syncthreads();
  }
  if (t == 0) {
    atomicAdd(&accum[co*4+0], r0[0]);
    atomicAdd(&accum[co*4+1], r1[0]);
    atomicAdd(&accum[co*4+2], r2[0]);
    atomicAdd(&accum[co*4+3], r3[0]);
  }
}

__global__ __launch_bounds__(256) void stats_i16_kernel(
    const int16_t* __restrict__ buf, int* __restrict__ accum,
    int s_sp, int pairs_per_block) {
  int co = blockIdx.x, slice = blockIdx.y;
  int p0i = slice * pairs_per_block;
  int psum = 0, nsum = 0, psq = 0, nsq = 0;
  for (int i = threadIdx.x; i < pairs_per_block; i += 256) {
    int flat = (p0i + i) * 2;
    int n = flat / s_sp, hw = flat % s_sp;
    short2 v = *reinterpret_cast<const short2*>(buf + (size_t)(n*COUT + co)*s_sp + hw);
    int vs[2] = {v.x, v.y};
    #pragma unroll
    for (int k = 0; k < 2; ++k) {
      int f = vs[k];
      if (f > 0) { psum += f; psq += f*f; } else { nsum += f; nsq += f*f; }
    }
  }
  __shared__ int r0[256], r1[256], r2[256], r3[256];
  int t = threadIdx.x;
  r0[t] = psum; r1[t] = nsum; r2[t] = psq; r3[t] = nsq;
  __syncthreads();
  for (int s = 128; s > 0; s >>= 1) {
    if (t < s) { r0[t]+=r0[t+s]; r1[t]+=r1[t+s]; r2[t]+=r2[t+s]; r3[t]+=r3[t+s]; }
    __syncthreads();
  }
  if (t == 0) {
    atomicAdd(&accum[co*4+0], r0[0]);
    atomicAdd(&accum[co*4+1], r1[0]);
    atomicAdd(&accum[co*4+2], r2[0]);
    atomicAdd(&accum[co*4+3], r3[0]);
  }
}

// ---------------- thresholds: sign(BN(prelu(v))) == (v>=Tpos) - (v<=Tneg) ----------------
__global__ __launch_bounds__(256) void thr_kernel(
    const int* __restrict__ accum, const float* __restrict__ a,
    const float* __restrict__ g, const float* __restrict__ b,
    float inv_ns, int vlo, int vhi,
    int* __restrict__ Tpos, int* __restrict__ Tneg) {
  int co = threadIdx.x;
  float av = a[co], sc, sh;
  bn_finalize(accum + co*4, av, g[co], b[co], inv_ns, sc, sh);
  int tp = vhi + 1, tn = vlo - 1;
  for (int v = vlo; v <= vhi; ++v) {
    float f = (float)v;
    float p = f > 0.f ? f : av*f;
    float tv = p*sc + sh;
    if (tv > 0.f && v < tp) tp = v;    // min v with tv>0
    if (tv < 0.f && v > tn) tn = v;    // max v with tv<0
  }
  Tpos[co] = tp;
  Tneg[co] = tn;
}

// ---------------- depthwise 3x3 s2 p1: LDS-staged signs, 8 slabs/block ----------------
// LDS tile: sl[slab][57 rows][68 bytes]; row p = ih+1, data cols 4..59 (col = iw+4).
// Staged bytes are thresholded SIGNS (-1/0/1); zero-filled pad is the conv's zero pad
// (correct because pad is applied AFTER sign in the reference).
#define DW_SLABS 8
#define DW_RB    68      // row stride bytes (68 -> banks differ by 2 per ho: 2-way, free)
__global__ __launch_bounds__(256) void dw_kernel(
    const int8_t* __restrict__ out1, const int8_t* __restrict__ wdws,
    const int* __restrict__ Tp1, const int* __restrict__ Tn1,
    int8_t* __restrict__ out2) {
  __shared__ int8_t sl[DW_SLABS][57][DW_RB];   // 30,464 B
  int tid = threadIdx.x;
  int nc0 = blockIdx.x * DW_SLABS;

  int* slw = (int*)&sl[0][0][0];
  #pragma unroll
  for (int i = tid; i < DW_SLABS*57*DW_RB/4; i += 256) slw[i] = 0;
  __syncthreads();

  // stage: 8 slabs x 784 dwords, coalesced global reads, threshold to signs
  for (int i = tid; i < DW_SLABS*784; i += 256) {
    int slab = i / 784;
    int d    = i - slab*784;
    int ih   = d / 14;
    int iwd  = d - ih*14;
    int co   = (nc0 + slab) & (COUT-1);
    int Tp = Tp1[co], Tn = Tn1[co];
    uint32_t v4 = ((const uint32_t*)(out1 + (size_t)(nc0 + slab)*S1))[d];
    uint32_t s4 = 0;
    #pragma unroll
    for (int k = 0; k < 4; ++k) {
      int v = (int)(int8_t)(v4 >> (8*k));
      int s = (v >= Tp) - (v <= Tn);
      s4 |= (uint32_t)(s & 0xff) << (8*k);
    }
    *(uint32_t*)&sl[slab][ih + 1][4 + 4*iwd] = s4;
  }
  __syncthreads();

  // compute: thread t < 224 handles one output row (slab, ho)
  if (tid < DW_SLABS*HO) {
    int slab = tid / HO;
    int ho   = tid - slab*HO;
    int nc = nc0 + slab;
    int co = nc & (COUT-1);
    int wv[9];
    #pragma unroll
    for (int k = 0; k < 9; ++k) wv[k] = wdws[co*9 + k];
    const uint32_t* r0 = (const uint32_t*)&sl[slab][2*ho    ][4];
    const uint32_t* r1 = (const uint32_t*)&sl[slab][2*ho + 1][4];
    const uint32_t* r2 = (const uint32_t*)&sl[slab][2*ho + 2][4];
    uint32_t* o32 = (uint32_t*)(out2 + (size_t)nc*S2 + ho*WO);
    int c0 = 0, c1 = 0, c2 = 0;    // carry col (iw = 4q-1); init 0 = left pad
    uint32_t obuf = 0;
    #pragma unroll
    for (int q = 0; q < 14; ++q) {
      uint32_t d0 = r0[q], d1 = r1[q], d2 = r2[q];
      int s00=(int)(int8_t)d0, s01=(int)(int8_t)(d0>>8), s02=(int)(int8_t)(d0>>16), s03=(int)(int8_t)(d0>>24);
      int s10=(int)(int8_t)d1, s11=(int)(int8_t)(d1>>8), s12=(int)(int8_t)(d1>>16), s13=(int)(int8_t)(d1>>24);
      int s20=(int)(int8_t)d2, s21=(int)(int8_t)(d2>>8), s22=(int)(int8_t)(d2>>16), s23=(int)(int8_t)(d2>>24);
      int a0 = c0*wv[0] + s00*wv[1] + s01*wv[2]
             + c1*wv[3] + s10*wv[4] + s11*wv[5]
             + c2*wv[6] + s20*wv[7] + s21*wv[8];
      int a1 = s01*wv[0] + s02*wv[1] + s03*wv[2]
             + s11*wv[3] + s12*wv[4] + s13*wv[5]
             + s21*wv[6] + s22*wv[7] + s23*wv[8];
      c0 = s03; c1 = s13; c2 = s23;
      if ((q & 1) == 0) {
        obuf = (uint32_t)(a0 & 0xff) | ((uint32_t)(a1 & 0xff) << 8);
      } else {
        obuf |= ((uint32_t)(a0 & 0xff) << 16) | ((uint32_t)(a1 & 0xff) << 24);
        o32[q >> 1] = obuf;
      }
    }
  }
}

// ---------------- pack sign(BN2(prelu(out2))) via thresholds, split over wdx ----------------
__global__ __launch_bounds__(256) void pack2_kernel(
    const int8_t* __restrict__ out2,
    const int* __restrict__ Tp2, const int* __restrict__ Tn2,
    uint32_t* __restrict__ xb2) {
  int m = blockIdx.x*256 + threadIdx.x;   // n*S2 + hw
  int wdx = blockIdx.y;                   // 0..7
  int n = m / S2, hw = m % S2;
  uint32_t p = 0, q = 0;
  #pragma unroll
  for (int j = 0; j < 32; ++j) {
    int c = wdx*32 + j;
    int v = out2[(size_t)(n*COUT + c)*S2 + hw];
    p |= (uint32_t)(v >= Tp2[c]) << j;
    q |= (uint32_t)(v <= Tn2[c]) << j;
  }
  xb2[(size_t)m*16 + wdx    ] = p;
  xb2[(size_t)m*16 + 8 + wdx] = q;
}

// ---------------- conv3: binary 1x1 256->256 with XOR fast path ----------------
__global__ __launch_bounds__(256) void conv3_kernel(
    const uint32_t* __restrict__ xb2, const uint32_t* __restrict__ wb3,
    int16_t* __restrict__ out3) {
  int m = blockIdx.x*256 + threadIdx.x;   // NS2
  int n = m / S2, hw = m % S2;
  const uint32_t* xw = xb2 + (size_t)m*16;
  uint32_t P[8], Q[8];
  #pragma unroll
  for (int i = 0; i < 8; ++i) { P[i] = xw[i]; Q[i] = xw[8+i]; }
  int co0 = blockIdx.y * 32;
  size_t obase = ((size_t)n*COUT)*S2 + hw;
  uint32_t allm = 0xffffffffu;
  #pragma unroll
  for (int i = 0; i < 8; ++i) allm &= (P[i] | Q[i]);
  if (allm == 0xffffffffu) {
    #pragma unroll 2
    for (int co = co0; co < co0 + 32; ++co) {
      const uint32_t* w = wb3 + (size_t)co*16;
      int s = 0;
      #pragma unroll
      for (int i = 0; i < 8; ++i) s += __popc(P[i] ^ w[i]);
      out3[obase + (size_t)co*S2] = (int16_t)(256 - 2*s);
    }
  } else {
    #pragma unroll 2
    for (int co = co0; co < co0 + 32; ++co) {
      const uint32_t* w = wb3 + (size_t)co*16;
      int acc = 0;
      #pragma unroll
      for (int i = 0; i < 8; ++i) {
        uint32_t wp = w[i], wn = w[8+i];
        acc += __popc(P[i]&wp) + __popc(Q[i]&wn) - __popc(P[i]&wn) - __popc(Q[i]&wp);
      }
      out3[obase + (size_t)co*S2] = (int16_t)acc;
    }
  }
}

// ---------------- fused residual (bf16 MFMA GEMM) + BN3(prelu(out3)) + add ----------------
__global__ __launch_bounds__(256) void resfinal_kernel(
    const uint16_t* __restrict__ xg, const uint16_t* __restrict__ wb,
    const int16_t* __restrict__ out3,
    const float* __restrict__ a3, const float* __restrict__ g3,
    const float* __restrict__ b3, const int* __restrict__ acc3,
    float* __restrict__ out) {
  int lane = threadIdx.x & 63;
  int wid  = threadIdx.x >> 6;
  int m0  = blockIdx.x*64 + wid*16;
  int co0 = blockIdx.y*64;
  int r16 = lane & 15, hi = lane >> 4;
  int koff = hi * 8;

  const bf16x8* arow = (const bf16x8*)(xg + (size_t)(m0 + r16)*CIN + koff);
  bf16x8 af0 = arow[0], af1 = arow[4], af2 = arow[8], af3 = arow[12];

  f32x4 d0, d1, d2, d3;
  {
    const bf16x8* brow = (const bf16x8*)(wb + (size_t)(co0 + r16)*CIN + koff);
    f32x4 a = {0.f,0.f,0.f,0.f};
    a = __builtin_amdgcn_mfma_f32_16x16x32_bf16(af0, brow[0],  a, 0,0,0);
    a = __builtin_amdgcn_mfma_f32_16x16x32_bf16(af1, brow[4],  a, 0,0,0);
    a = __builtin_amdgcn_mfma_f32_16x16x32_bf16(af2, brow[8],  a, 0,0,0);
    a = __builtin_amdgcn_mfma_f32_16x16x32_bf16(af3, brow[12], a, 0,0,0);
    d0 = a;
  }
  {
    const bf16x8* brow = (const bf16x8*)(wb + (size_t)(co0 + 16 + r16)*CIN + koff);
    f32x4 a = {0.f,0.f,0.f,0.f};
    a = __builtin_amdgcn_mfma_f32_16x16x32_bf16(af0, brow[0],  a, 0,0,0);
    a = __builtin_amdgcn_mfma_f32_16x16x32_bf16(af1, brow[4],  a, 0,0,0);
    a = __builtin_amdgcn_mfma_f32_16x16x32_bf16(af2, brow[8],  a, 0,0,0);
    a = __builtin_amdgcn_mfma_f32_16x16x32_bf16(af3, brow[12], a, 0,0,0);
    d1 = a;
  }
  {
    const bf16x8* brow = (const bf16x8*)(wb + (size_t)(co0 + 32 + r16)*CIN + koff);
    f32x4 a = {0.f,0.f,0.f,0.f};
    a = __builtin_amdgcn_mfma_f32_16x16x32_bf16(af0, brow[0],  a, 0,0,0);
    a = __builtin_amdgcn_mfma_f32_16x16x32_bf16(af1, brow[4],  a, 0,0,0);
    a = __builtin_amdgcn_mfma_f32_16x16x32_bf16(af2, brow[8],  a, 0,0,0);
    a = __builtin_amdgcn_mfma_f32_16x16x32_bf16(af3, brow[12], a, 0,0,0);
    d2 = a;
  }
  {
    const bf16x8* brow = (const bf16x8*)(wb + (size_t)(co0 + 48 + r16)*CIN + koff);
    f32x4 a = {0.f,0.f,0.f,0.f};
    a = __builtin_amdgcn_mfma_f32_16x16x32_bf16(af0, brow[0],  a, 0,0,0);
    a = __builtin_amdgcn_mfma_f32_16x16x32_bf16(af1, brow[4],  a, 0,0,0);
    a = __builtin_amdgcn_mfma_f32_16x16x32_bf16(af2, brow[8],  a, 0,0,0);
    a = __builtin_amdgcn_mfma_f32_16x16x32_bf16(af3, brow[12], a, 0,0,0);
    d3 = a;
  }

  int mrow = m0 + hi*4;
  int n  = mrow / S2;               // 16-m tiles never straddle n (784 % 16 == 0)
  int hw = mrow - n*S2;
  f32x4 dd[4] = {d0, d1, d2, d3};
  #pragma unroll
  for (int t = 0; t < 4; ++t) {
    int co = co0 + t*16 + r16;
    float av = a3[co], sc, sh;
    bn_finalize(acc3 + co*4, av, g3[co], b3[co], 1.f/NS2, sc, sh);
    size_t o = ((size_t)n*COUT + co)*S2 + hw;
    #pragma unroll
    for (int r = 0; r < 4; ++r) {
      float f = (float)out3[o + r];
      float pp = f > 0.f ? f : av*f;
      out[o + r] = pp*sc + sh + dd[t][r];
    }
  }
}

extern "C" void kernel_launch(void* const* d_in, const int* in_sizes, int n_in,
                              void* d_out, int out_size, void* d_ws, size_t ws_size,
                              hipStream_t stream) {
  (void)in_sizes; (void)n_in; (void)out_size; (void)ws_size;
  const float* x    = (const float*)d_in[0];
  const float* w1   = (const float*)d_in[1];
  const float* a1   = (const float*)d_in[2];
  const float* g1   = (const float*)d_in[3];
  const float* b1   = (const float*)d_in[4];
  const float* wdw  = (const float*)d_in[5];
  const float* a2   = (const float*)d_in[6];
  const float* g2   = (const float*)d_in[7];
  const float* b2   = (const float*)d_in[8];
  const float* w3   = (const float*)d_in[9];
  const float* a3   = (const float*)d_in[10];
  const float* g3   = (const float*)d_in[11];
  const float* b3   = (const float*)d_in[12];
  const float* wadj = (const float*)d_in[13];
  float* out = (float*)d_out;

  char* ws = (char*)d_ws;
  uint32_t* xbits = (uint32_t*)(ws + OFF_XBITS);
  uint32_t* wb1   = (uint32_t*)(ws + OFF_WB1);
  uint32_t* wb3   = (uint32_t*)(ws + OFF_WB3);
  int8_t*   wdws  = (int8_t*)  (ws + OFF_WDW);
  int*      acc1  = (int*)     (ws + OFF_ACC);
  int*      acc2  = acc1 + 256*4;
  int*      acc3  = acc2 + 256*4;
  int*      thr   = (int*)     (ws + OFF_THR);   // [4][256]: Tp1,Tn1,Tp2,Tn2
  int*      Tp1 = thr, *Tn1 = thr + 256, *Tp2 = thr + 512, *Tn2 = thr + 768;
  uint32_t* wbadj = (uint32_t*)(ws + OFF_WBADJ);
  uint32_t* xg    = (uint32_t*)(ws + OFF_XG);
  int8_t*   out1  = (int8_t*)  (ws + OFF_OUT1);
  int8_t*   out2  = (int8_t*)  (ws + OFF_OUT2);
  uint32_t* xb2   = (uint32_t*)(ws + OFF_XB2);
  int16_t*  out3  = (int16_t*) (ws + OFF_OUT3);

  packx_kernel<<<dim3(NS1/256, 4), 256, 0, stream>>>(
      x, xbits, xg, w1, w3, wdw, wadj, wb1, wb3, wdws, wbadj, acc1);
  conv1_kernel<<<dim3(NS1/256, 8), 256, 0, stream>>>(xbits, wb1, out1);
  stats_i8_kernel<<<dim3(256, 8), 256, 0, stream>>>(out1, acc1, S1, 3136);
  thr_kernel<<<1, 256, 0, stream>>>(acc1, a1, g1, b1, 1.f/NS1, -128, 127, Tp1, Tn1);
  dw_kernel<<<NB*COUT/DW_SLABS, 256, 0, stream>>>(out1, wdws, Tp1, Tn1, out2);
  stats_i8_kernel<<<dim3(256, 4), 256, 0, stream>>>(out2, acc2, S2, 1568);
  thr_kernel<<<1, 256, 0, stream>>>(acc2, a2, g2, b2, 1.f/NS2, -9, 9, Tp2, Tn2);
  pack2_kernel<<<dim3(NS2/256, 8), 256, 0, stream>>>(out2, Tp2, Tn2, xb2);
  conv3_kernel<<<dim3(NS2/256, 8), 256, 0, stream>>>(xb2, wb3, out3);
  stats_i16_kernel<<<dim3(256, 4), 256, 0, stream>>>(out3, acc3, S2, 3136);
  resfinal_kernel<<<dim3(NS2/64, COUT/64), 256, 0, stream>>>(
      (const uint16_t*)xg, (const uint16_t*)wbadj, out3, a3, g3, b3, acc3, out);
}

// Round 10
// 109.962 us; speedup vs baseline: 2.0928x; 1.2117x over previous
//
#include <hip/hip_runtime.h>
#include <stdint.h>

// ---- problem dims ----
#define NB   32
#define CIN  128
#define COUT 256
#define HH   56
#define WW   56
#define S1   (HH*WW)      // 3136
#define HO   28
#define WO   28
#define S2   (HO*WO)      // 784
#define NS1  (NB*S1)      // 100352
#define NS2  (NB*S2)      // 25088
#define TOT2 (NS2*COUT)   // 6422528
#define EPSV 1e-5f

// ---- workspace layout (bytes) ----
constexpr size_t OFF_XBITS = 0;                                 // NS1*8*4 = 3,211,264
constexpr size_t OFF_WB1   = OFF_XBITS + (size_t)NS1*8*4;       // 8 KB
constexpr size_t OFF_WB3   = OFF_WB1 + 256*8*4;                 // 16 KB
constexpr size_t OFF_WDW   = OFF_WB3 + 256*16*4;                // 4 KB
constexpr size_t OFF_ACC   = OFF_WDW + 4096;                    // 12 KB
constexpr size_t OFF_WBADJ = OFF_ACC + 3*256*4*sizeof(int);     // 256*128*2 = 65,536
constexpr size_t OFF_XG    = OFF_WBADJ + (size_t)COUT*CIN*2;    // NS2*128*2 = 6,422,528
constexpr size_t OFF_OUT1  = OFF_XG + (size_t)NS2*CIN*2;        // NS1*COUT i8 = 25,690,112
constexpr size_t OFF_OUT2  = OFF_OUT1 + (size_t)NS1*COUT;       // i8 6,422,528
constexpr size_t OFF_XB2   = OFF_OUT2 + (size_t)TOT2;           // NS2*16*4 = 1,605,632
constexpr size_t OFF_OUT3  = OFF_XB2 + (size_t)NS2*16*4;        // i16 12,845,056
// total ~56 MB

typedef __attribute__((ext_vector_type(8))) short bf16x8;
typedef __attribute__((ext_vector_type(4))) float f32x4;

__device__ __forceinline__ uint32_t f2bf(float v) {
  uint32_t u = __float_as_uint(v);
  return (u + 0x7fffu + ((u >> 16) & 1u)) >> 16;   // RNE bf16 bits
}

// finalize BN scale/shift from exact integer sums of prelu output
__device__ __forceinline__ void bn_finalize(const int* __restrict__ acc4,
                                            float a, float g, float b, float inv_ns,
                                            float& sc, float& sh) {
  float ps = (float)acc4[0];   // sum of v where v>0
  float ng = (float)acc4[1];   // sum of v where v<0
  float pq = (float)acc4[2];   // sum of v^2 where v>0
  float nq = (float)acc4[3];   // sum of v^2 where v<0
  float mean = (ps + a*ng) * inv_ns;
  float ex2  = (pq + a*a*nq) * inv_ns;
  float var  = ex2 - mean*mean;
  float rs   = rsqrtf(var + EPSV);
  sc = rs * g;
  sh = b - mean * sc;
}

// ---------------- pack x into bitplanes + bf16 stride-2 tile, fused weight pack ----------------
__global__ __launch_bounds__(256) void packx_kernel(
    const float* __restrict__ x, uint32_t* __restrict__ xbits,
    uint32_t* __restrict__ xg,
    const float* __restrict__ w1, const float* __restrict__ w3,
    const float* __restrict__ wdw, const float* __restrict__ wadj,
    uint32_t* __restrict__ wb1, uint32_t* __restrict__ wb3,
    int8_t* __restrict__ wdws, uint32_t* __restrict__ wbadj,
    int* __restrict__ accbase) {
  int wdx = blockIdx.y;                     // 0..3
  // fused weight pack + acc zero: wave 0 of blocks (bx<256, wdx==0)
  if (wdx == 0 && blockIdx.x < 256 && threadIdx.x < 64) {
    int co = blockIdx.x;
    int l  = threadIdx.x;
    if (l < 12) {
      int set = l >> 2, k = l & 3;
      accbase[set*1024 + co*4 + k] = 0;
    }
    for (int h = 0; h < 2; ++h) {
      float v = w1[(size_t)co*CIN + h*64 + l];
      unsigned long long bp = __ballot(v > 0.f);
      unsigned long long bn = __ballot(v < 0.f);
      if (l == 0) {
        wb1[co*8 + 2*h    ] = (uint32_t)bp;
        wb1[co*8 + 2*h + 1] = (uint32_t)(bp >> 32);
        wb1[co*8 + 4 + 2*h    ] = (uint32_t)bn;
        wb1[co*8 + 4 + 2*h + 1] = (uint32_t)(bn >> 32);
      }
    }
    for (int h = 0; h < 4; ++h) {
      float v = w3[(size_t)co*COUT + h*64 + l];
      unsigned long long bp = __ballot(v > 0.f);
      unsigned long long bn = __ballot(v < 0.f);
      if (l == 0) {
        wb3[co*16 + 2*h    ] = (uint32_t)bp;
        wb3[co*16 + 2*h + 1] = (uint32_t)(bp >> 32);
        wb3[co*16 + 8 + 2*h    ] = (uint32_t)bn;
        wb3[co*16 + 8 + 2*h + 1] = (uint32_t)(bn >> 32);
      }
    }
    if (l < 9) {
      float v = wdw[co*9 + l];
      wdws[co*9 + l] = (int8_t)((v > 0.f) - (v < 0.f));
    }
    {
      float v0 = wadj[(size_t)co*CIN + 2*l];
      float v1 = wadj[(size_t)co*CIN + 2*l + 1];
      wbadj[co*64 + l] = f2bf(v0) | (f2bf(v1) << 16);
    }
  }

  int m = blockIdx.x*256 + threadIdx.x;     // m = n*S1 + hw
  int n = m / S1, hw = m % S1;
  size_t base = ((size_t)n*CIN + wdx*32)*S1 + hw;
  uint32_t p = 0, q = 0;
  uint32_t bv[16];
  #pragma unroll
  for (int j = 0; j < 32; ++j) {
    float v = x[base + (size_t)j*S1];
    p |= (uint32_t)(v > 0.f) << j;
    q |= (uint32_t)(v < 0.f) << j;
    uint32_t b = f2bf(v);
    if (j & 1) bv[j >> 1] |= b << 16; else bv[j >> 1] = b;
  }
  xbits[(size_t)m*8 + wdx    ] = p;
  xbits[(size_t)m*8 + 4 + wdx] = q;
  int h = hw / WW, w = hw % WW;
  if (((h | w) & 1) == 0) {
    int m2 = n*S2 + (h >> 1)*WO + (w >> 1);
    uint4* dst = (uint4*)(xg + (size_t)m2*64 + wdx*16);
    dst[0] = make_uint4(bv[0],  bv[1],  bv[2],  bv[3]);
    dst[1] = make_uint4(bv[4],  bv[5],  bv[6],  bv[7]);
    dst[2] = make_uint4(bv[8],  bv[9],  bv[10], bv[11]);
    dst[3] = make_uint4(bv[12], bv[13], bv[14], bv[15]);
  }
}

// ---------------- conv1: binary 1x1 via XOR popcount (fast path) ----------------
__global__ __launch_bounds__(256) void conv1_kernel(
    const uint32_t* __restrict__ xb, const uint32_t* __restrict__ wb,
    int8_t* __restrict__ out1) {
  int m = blockIdx.x*256 + threadIdx.x;
  int n = m / S1, hw = m % S1;
  const uint32_t* xw = xb + (size_t)m*8;
  uint32_t p0 = xw[0], p1 = xw[1], p2 = xw[2], p3 = xw[3];
  uint32_t q0 = xw[4], q1 = xw[5], q2 = xw[6], q3 = xw[7];
  int co0 = blockIdx.y * 32;
  size_t obase = ((size_t)n*COUT)*S1 + hw;
  bool nozero = (((p0|q0) & (p1|q1) & (p2|q2) & (p3|q3)) == 0xffffffffu);
  if (nozero) {
    #pragma unroll 4
    for (int co = co0; co < co0 + 32; ++co) {
      const uint32_t* w8 = wb + (size_t)co*8;
      int s = __popc(p0 ^ w8[0]) + __popc(p1 ^ w8[1])
            + __popc(p2 ^ w8[2]) + __popc(p3 ^ w8[3]);
      int acc = 128 - 2*s;
      if (acc > 127) acc = 127;
      out1[obase + (size_t)co*S1] = (int8_t)acc;
    }
  } else {
    #pragma unroll 4
    for (int co = co0; co < co0 + 32; ++co) {
      const uint32_t* w8 = wb + (size_t)co*8;
      uint32_t a0 = w8[0], a1 = w8[1], a2 = w8[2], a3 = w8[3];
      uint32_t b0 = w8[4], b1 = w8[5], b2 = w8[6], b3 = w8[7];
      int acc = __popc(p0&a0) + __popc(p1&a1) + __popc(p2&a2) + __popc(p3&a3)
              + __popc(q0&b0) + __popc(q1&b1) + __popc(q2&b2) + __popc(q3&b3)
              - __popc(p0&b0) - __popc(p1&b1) - __popc(p2&b2) - __popc(p3&b3)
              - __popc(q0&a0) - __popc(q1&a1) - __popc(q2&a2) - __popc(q3&a3);
      if (acc > 127) acc = 127;
      out1[obase + (size_t)co*S1] = (int8_t)acc;
    }
  }
}

// ---------------- per-channel integer stats (int8 buffer), 16B loads ----------------
__global__ __launch_bounds__(256) void stats_i8_kernel(
    const int8_t* __restrict__ buf, int* __restrict__ accum,
    int s_sp, int v16_per_block) {
  int co = blockIdx.x, slice = blockIdx.y;
  int base16 = slice * v16_per_block;
  int psum = 0, nsum = 0, psq = 0, nsq = 0;
  for (int i = threadIdx.x; i < v16_per_block; i += 256) {
    int flat = (base16 + i) * 16;
    int n = flat / s_sp, hw = flat % s_sp;
    int4 v = *reinterpret_cast<const int4*>(buf + (size_t)(n*COUT + co)*s_sp + hw);
    int ws[4] = {v.x, v.y, v.z, v.w};
    #pragma unroll
    for (int d = 0; d < 4; ++d) {
      #pragma unroll
      for (int k = 0; k < 4; ++k) {
        int f = (int)(int8_t)(ws[d] >> (8*k));
        if (f > 0) { psum += f; psq += f*f; } else { nsum += f; nsq += f*f; }
      }
    }
  }
  __shared__ int r0[256], r1[256], r2[256], r3[256];
  int t = threadIdx.x;
  r0[t] = psum; r1[t] = nsum; r2[t] = psq; r3[t] = nsq;
  __syncthreads();
  for (int s = 128; s > 0; s >>= 1) {
    if (t < s) { r0[t]+=r0[t+s]; r1[t]+=r1[t+s]; r2[t]+=r2[t+s]; r3[t]+=r3[t+s]; }
    __syncthreads();
  }
  if (t == 0) {
    atomicAdd(&accum[co*4+0], r0[0]);
    atomicAdd(&accum[co*4+1], r1[0]);
    atomicAdd(&accum[co*4+2], r2[0]);
    atomicAdd(&accum[co*4+3], r3[0]);
  }
}

// ---------------- per-channel integer stats (int16 buffer), 16B loads ----------------
__global__ __launch_bounds__(256) void stats_i16_kernel(
    const int16_t* __restrict__ buf, int* __restrict__ accum,
    int s_sp, int v8_per_block) {
  int co = blockIdx.x, slice = blockIdx.y;
  int base8 = slice * v8_per_block;
  int psum = 0, nsum = 0, psq = 0, nsq = 0;
  for (int i = threadIdx.x; i < v8_per_block; i += 256) {
    int flat = (base8 + i) * 8;
    int n = flat / s_sp, hw = flat % s_sp;
    int4 v = *reinterpret_cast<const int4*>(buf + (size_t)(n*COUT + co)*s_sp + hw);
    int ws[4] = {v.x, v.y, v.z, v.w};
    #pragma unroll
    for (int d = 0; d < 4; ++d) {
      int lo = (int)(short)(ws[d] & 0xffff);
      int hi = (int)(short)(ws[d] >> 16);
      if (lo > 0) { psum += lo; psq += lo*lo; } else { nsum += lo; nsq += lo*lo; }
      if (hi > 0) { psum += hi; psq += hi*hi; } else { nsum += hi; nsq += hi*hi; }
    }
  }
  __shared__ int r0[256], r1[256], r2[256], r3[256];
  int t = threadIdx.x;
  r0[t] = psum; r1[t] = nsum; r2[t] = psq; r3[t] = nsq;
  __syncthreads();
  for (int s = 128; s > 0; s >>= 1) {
    if (t < s) { r0[t]+=r0[t+s]; r1[t]+=r1[t+s]; r2[t]+=r2[t+s]; r3[t]+=r3[t+s]; }
    __syncthreads();
  }
  if (t == 0) {
    atomicAdd(&accum[co*4+0], r0[0]);
    atomicAdd(&accum[co*4+1], r1[0]);
    atomicAdd(&accum[co*4+2], r2[0]);
    atomicAdd(&accum[co*4+3], r3[0]);
  }
}

// ---------------- depthwise 3x3 s2 p1: LDS signs, inline thr1, fused stats2 ----------------
// LDS tile: sl[slab][57 rows][68 bytes]; row p = ih+1, data cols 4..59.
// Thresholds computed in-block (identical float expr, brute force over v in [-128,127]).
#define DW_SLABS 8
#define DW_RB    68
__global__ __launch_bounds__(256) void dw_kernel(
    const int8_t* __restrict__ out1, const int8_t* __restrict__ wdws,
    const int* __restrict__ acc1, const float* __restrict__ a1,
    const float* __restrict__ g1, const float* __restrict__ b1,
    int8_t* __restrict__ out2, int* __restrict__ accum2) {
  __shared__ int8_t sl[DW_SLABS][57][DW_RB];   // 30,464 B
  __shared__ int sTp[DW_SLABS], sTn[DW_SLABS], sAcc[DW_SLABS][4];
  int tid = threadIdx.x;
  int nc0 = blockIdx.x * DW_SLABS;
  int co0 = nc0 & (COUT-1);                    // 256 % 8 == 0: no wrap within block

  // phase A: init LDS
  int* slw = (int*)&sl[0][0][0];
  #pragma unroll
  for (int i = tid; i < DW_SLABS*57*DW_RB/4; i += 256) slw[i] = 0;
  if (tid < DW_SLABS) { sTp[tid] = 128; sTn[tid] = -129; }
  if (tid < DW_SLABS*4) sAcc[tid >> 2][tid & 3] = 0;
  __syncthreads();

  // phase B: inline thresholds (32 threads per slab, 8 candidate v each)
  {
    int slab = tid >> 5;
    int co = co0 + slab;
    float av = a1[co], sc, sh;
    bn_finalize(acc1 + co*4, av, g1[co], b1[co], 1.f/NS1, sc, sh);
    int tp = 128, tn = -129;
    int v0 = -128 + (tid & 31)*8;
    #pragma unroll
    for (int k = 0; k < 8; ++k) {
      int v = v0 + k;
      float f = (float)v;
      float pr = f > 0.f ? f : av*f;
      float tv = pr*sc + sh;
      if (tv > 0.f && v < tp) tp = v;
      if (tv < 0.f && v > tn) tn = v;
    }
    atomicMin(&sTp[slab], tp);
    atomicMax(&sTn[slab], tn);
  }
  __syncthreads();

  // phase C: stage signs (coalesced dword reads, threshold once per value)
  for (int i = tid; i < DW_SLABS*784; i += 256) {
    int slab = i / 784;
    int d    = i - slab*784;
    int ih   = d / 14;
    int iwd  = d - ih*14;
    int Tp = sTp[slab], Tn = sTn[slab];
    uint32_t v4 = ((const uint32_t*)(out1 + (size_t)(nc0 + slab)*S1))[d];
    uint32_t s4 = 0;
    #pragma unroll
    for (int k = 0; k < 4; ++k) {
      int v = (int)(int8_t)(v4 >> (8*k));
      int s = (v >= Tp) - (v <= Tn);
      s4 |= (uint32_t)(s & 0xff) << (8*k);
    }
    *(uint32_t*)&sl[slab][ih + 1][4 + 4*iwd] = s4;
  }
  __syncthreads();

  // phase D: compute one output row per thread (slab, ho) + local stats
  int psum = 0, nsum = 0, psq = 0, nsq = 0;
  int slabD = tid / HO;
  if (tid < DW_SLABS*HO) {
    int ho   = tid - slabD*HO;
    int nc = nc0 + slabD;
    int co = co0 + slabD;
    int wv[9];
    #pragma unroll
    for (int k = 0; k < 9; ++k) wv[k] = wdws[co*9 + k];
    const uint32_t* r0 = (const uint32_t*)&sl[slabD][2*ho    ][4];
    const uint32_t* r1 = (const uint32_t*)&sl[slabD][2*ho + 1][4];
    const uint32_t* r2 = (const uint32_t*)&sl[slabD][2*ho + 2][4];
    uint32_t* o32 = (uint32_t*)(out2 + (size_t)nc*S2 + ho*WO);
    int c0 = 0, c1 = 0, c2 = 0;
    uint32_t obuf = 0;
    #pragma unroll
    for (int q = 0; q < 14; ++q) {
      uint32_t d0 = r0[q], d1 = r1[q], d2 = r2[q];
      int s00=(int)(int8_t)d0, s01=(int)(int8_t)(d0>>8), s02=(int)(int8_t)(d0>>16), s03=(int)(int8_t)(d0>>24);
      int s10=(int)(int8_t)d1, s11=(int)(int8_t)(d1>>8), s12=(int)(int8_t)(d1>>16), s13=(int)(int8_t)(d1>>24);
      int s20=(int)(int8_t)d2, s21=(int)(int8_t)(d2>>8), s22=(int)(int8_t)(d2>>16), s23=(int)(int8_t)(d2>>24);
      int a0 = c0*wv[0] + s00*wv[1] + s01*wv[2]
             + c1*wv[3] + s10*wv[4] + s11*wv[5]
             + c2*wv[6] + s20*wv[7] + s21*wv[8];
      int a1v = s01*wv[0] + s02*wv[1] + s03*wv[2]
              + s11*wv[3] + s12*wv[4] + s13*wv[5]
              + s21*wv[6] + s22*wv[7] + s23*wv[8];
      c0 = s03; c1 = s13; c2 = s23;
      if (a0 > 0) { psum += a0; psq += a0*a0; } else { nsum += a0; nsq += a0*a0; }
      if (a1v > 0) { psum += a1v; psq += a1v*a1v; } else { nsum += a1v; nsq += a1v*a1v; }
      if ((q & 1) == 0) {
        obuf = (uint32_t)(a0 & 0xff) | ((uint32_t)(a1v & 0xff) << 8);
      } else {
        obuf |= ((uint32_t)(a0 & 0xff) << 16) | ((uint32_t)(a1v & 0xff) << 24);
        o32[q >> 1] = obuf;
      }
    }
    atomicAdd(&sAcc[slabD][0], psum);
    atomicAdd(&sAcc[slabD][1], nsum);
    atomicAdd(&sAcc[slabD][2], psq);
    atomicAdd(&sAcc[slabD][3], nsq);
  }
  __syncthreads();

  // phase E: per-slab global atomics
  if (tid < DW_SLABS*4) {
    int slab = tid >> 2, k = tid & 3;
    atomicAdd(&accum2[(co0 + slab)*4 + k], sAcc[slab][k]);
  }
}

// ---------------- pack sign(BN2(prelu(out2))): inline thr2 + thresholds ----------------
__global__ __launch_bounds__(256) void pack2_kernel(
    const int8_t* __restrict__ out2, const int* __restrict__ acc2,
    const float* __restrict__ a2, const float* __restrict__ g2,
    const float* __restrict__ b2, uint32_t* __restrict__ xb2) {
  __shared__ int sTp[32], sTn[32];
  int wdx = blockIdx.y;                   // 0..7
  if (threadIdx.x < 32) {
    int c = wdx*32 + threadIdx.x;
    float av = a2[c], sc, sh;
    bn_finalize(acc2 + c*4, av, g2[c], b2[c], 1.f/NS2, sc, sh);
    int tp = 10, tn = -10;
    for (int v = -9; v <= 9; ++v) {
      float f = (float)v;
      float pr = f > 0.f ? f : av*f;
      float tv = pr*sc + sh;
      if (tv > 0.f && v < tp) tp = v;
      if (tv < 0.f && v > tn) tn = v;
    }
    sTp[threadIdx.x] = tp; sTn[threadIdx.x] = tn;
  }
  __syncthreads();
  int m = blockIdx.x*256 + threadIdx.x;   // n*S2 + hw
  int n = m / S2, hw = m % S2;
  uint32_t p = 0, q = 0;
  #pragma unroll
  for (int j = 0; j < 32; ++j) {
    int c = wdx*32 + j;
    int v = out2[(size_t)(n*COUT + c)*S2 + hw];
    p |= (uint32_t)(v >= sTp[j]) << j;
    q |= (uint32_t)(v <= sTn[j]) << j;
  }
  xb2[(size_t)m*16 + wdx    ] = p;
  xb2[(size_t)m*16 + 8 + wdx] = q;
}

// ---------------- conv3: binary 1x1 256->256 with XOR fast path ----------------
__global__ __launch_bounds__(256) void conv3_kernel(
    const uint32_t* __restrict__ xb2, const uint32_t* __restrict__ wb3,
    int16_t* __restrict__ out3) {
  int m = blockIdx.x*256 + threadIdx.x;   // NS2
  int n = m / S2, hw = m % S2;
  const uint32_t* xw = xb2 + (size_t)m*16;
  uint32_t P[8], Q[8];
  #pragma unroll
  for (int i = 0; i < 8; ++i) { P[i] = xw[i]; Q[i] = xw[8+i]; }
  int co0 = blockIdx.y * 32;
  size_t obase = ((size_t)n*COUT)*S2 + hw;
  uint32_t allm = 0xffffffffu;
  #pragma unroll
  for (int i = 0; i < 8; ++i) allm &= (P[i] | Q[i]);
  if (allm == 0xffffffffu) {
    #pragma unroll 2
    for (int co = co0; co < co0 + 32; ++co) {
      const uint32_t* w = wb3 + (size_t)co*16;
      int s = 0;
      #pragma unroll
      for (int i = 0; i < 8; ++i) s += __popc(P[i] ^ w[i]);
      out3[obase + (size_t)co*S2] = (int16_t)(256 - 2*s);
    }
  } else {
    #pragma unroll 2
    for (int co = co0; co < co0 + 32; ++co) {
      const uint32_t* w = wb3 + (size_t)co*16;
      int acc = 0;
      #pragma unroll
      for (int i = 0; i < 8; ++i) {
        uint32_t wp = w[i], wn = w[8+i];
        acc += __popc(P[i]&wp) + __popc(Q[i]&wn) - __popc(P[i]&wn) - __popc(Q[i]&wp);
      }
      out3[obase + (size_t)co*S2] = (int16_t)acc;
    }
  }
}

// ---------------- fused residual (bf16 MFMA GEMM) + BN3(prelu(out3)) + add ----------------
__global__ __launch_bounds__(256) void resfinal_kernel(
    const uint16_t* __restrict__ xg, const uint16_t* __restrict__ wb,
    const int16_t* __restrict__ out3,
    const float* __restrict__ a3, const float* __restrict__ g3,
    const float* __restrict__ b3, const int* __restrict__ acc3,
    float* __restrict__ out) {
  int lane = threadIdx.x & 63;
  int wid  = threadIdx.x >> 6;
  int m0  = blockIdx.x*64 + wid*16;
  int co0 = blockIdx.y*64;
  int r16 = lane & 15, hi = lane >> 4;
  int koff = hi * 8;

  const bf16x8* arow = (const bf16x8*)(xg + (size_t)(m0 + r16)*CIN + koff);
  bf16x8 af0 = arow[0], af1 = arow[4], af2 = arow[8], af3 = arow[12];

  f32x4 d0, d1, d2, d3;
  {
    const bf16x8* brow = (const bf16x8*)(wb + (size_t)(co0 + r16)*CIN + koff);
    f32x4 a = {0.f,0.f,0.f,0.f};
    a = __builtin_amdgcn_mfma_f32_16x16x32_bf16(af0, brow[0],  a, 0,0,0);
    a = __builtin_amdgcn_mfma_f32_16x16x32_bf16(af1, brow[4],  a, 0,0,0);
    a = __builtin_amdgcn_mfma_f32_16x16x32_bf16(af2, brow[8],  a, 0,0,0);
    a = __builtin_amdgcn_mfma_f32_16x16x32_bf16(af3, brow[12], a, 0,0,0);
    d0 = a;
  }
  {
    const bf16x8* brow = (const bf16x8*)(wb + (size_t)(co0 + 16 + r16)*CIN + koff);
    f32x4 a = {0.f,0.f,0.f,0.f};
    a = __builtin_amdgcn_mfma_f32_16x16x32_bf16(af0, brow[0],  a, 0,0,0);
    a = __builtin_amdgcn_mfma_f32_16x16x32_bf16(af1, brow[4],  a, 0,0,0);
    a = __builtin_amdgcn_mfma_f32_16x16x32_bf16(af2, brow[8],  a, 0,0,0);
    a = __builtin_amdgcn_mfma_f32_16x16x32_bf16(af3, brow[12], a, 0,0,0);
    d1 = a;
  }
  {
    const bf16x8* brow = (const bf16x8*)(wb + (size_t)(co0 + 32 + r16)*CIN + koff);
    f32x4 a = {0.f,0.f,0.f,0.f};
    a = __builtin_amdgcn_mfma_f32_16x16x32_bf16(af0, brow[0],  a, 0,0,0);
    a = __builtin_amdgcn_mfma_f32_16x16x32_bf16(af1, brow[4],  a, 0,0,0);
    a = __builtin_amdgcn_mfma_f32_16x16x32_bf16(af2, brow[8],  a, 0,0,0);
    a = __builtin_amdgcn_mfma_f32_16x16x32_bf16(af3, brow[12], a, 0,0,0);
    d2 = a;
  }
  {
    const bf16x8* brow = (const bf16x8*)(wb + (size_t)(co0 + 48 + r16)*CIN + koff);
    f32x4 a = {0.f,0.f,0.f,0.f};
    a = __builtin_amdgcn_mfma_f32_16x16x32_bf16(af0, brow[0],  a, 0,0,0);
    a = __builtin_amdgcn_mfma_f32_16x16x32_bf16(af1, brow[4],  a, 0,0,0);
    a = __builtin_amdgcn_mfma_f32_16x16x32_bf16(af2, brow[8],  a, 0,0,0);
    a = __builtin_amdgcn_mfma_f32_16x16x32_bf16(af3, brow[12], a, 0,0,0);
    d3 = a;
  }

  int mrow = m0 + hi*4;
  int n  = mrow / S2;               // 16-m tiles never straddle n (784 % 16 == 0)
  int hw = mrow - n*S2;
  f32x4 dd[4] = {d0, d1, d2, d3};
  #pragma unroll
  for (int t = 0; t < 4; ++t) {
    int co = co0 + t*16 + r16;
    float av = a3[co], sc, sh;
    bn_finalize(acc3 + co*4, av, g3[co], b3[co], 1.f/NS2, sc, sh);
    size_t o = ((size_t)n*COUT + co)*S2 + hw;
    #pragma unroll
    for (int r = 0; r < 4; ++r) {
      float f = (float)out3[o + r];
      float pp = f > 0.f ? f : av*f;
      out[o + r] = pp*sc + sh + dd[t][r];
    }
  }
}

extern "C" void kernel_launch(void* const* d_in, const int* in_sizes, int n_in,
                              void* d_out, int out_size, void* d_ws, size_t ws_size,
                              hipStream_t stream) {
  (void)in_sizes; (void)n_in; (void)out_size; (void)ws_size;
  const float* x    = (const float*)d_in[0];
  const float* w1   = (const float*)d_in[1];
  const float* a1   = (const float*)d_in[2];
  const float* g1   = (const float*)d_in[3];
  const float* b1   = (const float*)d_in[4];
  const float* wdw  = (const float*)d_in[5];
  const float* a2   = (const float*)d_in[6];
  const float* g2   = (const float*)d_in[7];
  const float* b2   = (const float*)d_in[8];
  const float* w3   = (const float*)d_in[9];
  const float* a3   = (const float*)d_in[10];
  const float* g3   = (const float*)d_in[11];
  const float* b3   = (const float*)d_in[12];
  const float* wadj = (const float*)d_in[13];
  float* out = (float*)d_out;

  char* ws = (char*)d_ws;
  uint32_t* xbits = (uint32_t*)(ws + OFF_XBITS);
  uint32_t* wb1   = (uint32_t*)(ws + OFF_WB1);
  uint32_t* wb3   = (uint32_t*)(ws + OFF_WB3);
  int8_t*   wdws  = (int8_t*)  (ws + OFF_WDW);
  int*      acc1  = (int*)     (ws + OFF_ACC);
  int*      acc2  = acc1 + 256*4;
  int*      acc3  = acc2 + 256*4;
  uint32_t* wbadj = (uint32_t*)(ws + OFF_WBADJ);
  uint32_t* xg    = (uint32_t*)(ws + OFF_XG);
  int8_t*   out1  = (int8_t*)  (ws + OFF_OUT1);
  int8_t*   out2  = (int8_t*)  (ws + OFF_OUT2);
  uint32_t* xb2   = (uint32_t*)(ws + OFF_XB2);
  int16_t*  out3  = (int16_t*) (ws + OFF_OUT3);

  packx_kernel<<<dim3(NS1/256, 4), 256, 0, stream>>>(
      x, xbits, xg, w1, w3, wdw, wadj, wb1, wb3, wdws, wbadj, acc1);
  conv1_kernel<<<dim3(NS1/256, 8), 256, 0, stream>>>(xbits, wb1, out1);
  // out1 stats: NS1/16 = 6272 16B-units per co, 4 slices of 1568
  stats_i8_kernel<<<dim3(256, 4), 256, 0, stream>>>(out1, acc1, S1, 1568);
  dw_kernel<<<NB*COUT/DW_SLABS, 256, 0, stream>>>(out1, wdws, acc1, a1, g1, b1, out2, acc2);
  pack2_kernel<<<dim3(NS2/256, 8), 256, 0, stream>>>(out2, acc2, a2, g2, b2, xb2);
  conv3_kernel<<<dim3(NS2/256, 8), 256, 0, stream>>>(xb2, wb3, out3);
  // out3 stats: NS2/8 = 3136 int4-units per co, 4 slices of 784
  stats_i16_kernel<<<dim3(256, 4), 256, 0, stream>>>(out3, acc3, S2, 784);
  resfinal_kernel<<<dim3(NS2/64, COUT/64), 256, 0, stream>>>(
      (const uint16_t*)xg, (const uint16_t*)wbadj, out3, a3, g3, b3, acc3, out);
}